// Round 7
// baseline (1921.624 us; speedup 1.0000x reference)
//
#include <hip/hip_runtime.h>
#include <math.h>

#define N_NODES 10000
#define N_EDGES 100000
#define N_GRAPH 64
#define CDIM 128
#define HCDIM 256
#define C3DIM 384

typedef unsigned short u16;
typedef __attribute__((ext_vector_type(8))) short bf16x8;
typedef __attribute__((ext_vector_type(4))) float f32x4;

__device__ __forceinline__ u16 f2bf(float f) {
  union { float f; unsigned int u; } x; x.f = f;
  unsigned int u = x.u + 0x7fffu + ((x.u >> 16) & 1u);
  return (u16)(u >> 16);
}
__device__ __forceinline__ float bf2f(u16 h) {
  union { unsigned int u; float f; } x; x.u = ((unsigned int)h) << 16;
  return x.f;
}

// ---------------- generic fp32 GEMM (odd-K, tiny) ----------------------------
template<int ACT>
__global__ __launch_bounds__(256) void gemm_kernel(
    const float* __restrict__ A, const float* __restrict__ W,
    const float* __restrict__ bias, float* __restrict__ Y,
    int M, int K, int N) {
  __shared__ float As[16][68];
  __shared__ float Bs[16][65];
  const int tid = threadIdx.x;
  const int bm = blockIdx.y * 64, bn = blockIdx.x * 64;
  const int tx = tid & 15, ty = tid >> 4;
  float acc[4][4] = {};
  for (int k0 = 0; k0 < K; k0 += 16) {
#pragma unroll
    for (int i = 0; i < 4; ++i) {
      int l = tid + i * 256;
      int kk = l & 15, m = l >> 4;
      int gm = bm + m, gk = k0 + kk;
      As[kk][m] = (gm < M && gk < K) ? A[(size_t)gm * K + gk] : 0.f;
    }
#pragma unroll
    for (int i = 0; i < 4; ++i) {
      int l = tid + i * 256;
      int n = l & 63, kk = l >> 6;
      int gk = k0 + kk, gn = bn + n;
      Bs[kk][n] = (gk < K && gn < N) ? W[(size_t)gk * N + gn] : 0.f;
    }
    __syncthreads();
#pragma unroll
    for (int kk = 0; kk < 16; ++kk) {
      float a[4], b[4];
#pragma unroll
      for (int i = 0; i < 4; ++i) a[i] = As[kk][ty * 4 + i];
#pragma unroll
      for (int j = 0; j < 4; ++j) b[j] = Bs[kk][tx * 4 + j];
#pragma unroll
      for (int i = 0; i < 4; ++i)
#pragma unroll
        for (int j = 0; j < 4; ++j) acc[i][j] += a[i] * b[j];
    }
    __syncthreads();
  }
#pragma unroll
  for (int i = 0; i < 4; ++i) {
    int gm = bm + ty * 4 + i;
    if (gm >= M) continue;
#pragma unroll
    for (int j = 0; j < 4; ++j) {
      int gn = bn + tx * 4 + j;
      if (gn >= N) continue;
      float val = acc[i][j] + (bias ? bias[gn] : 0.f);
      if (ACT == 1) val = val / (1.f + expf(-val));
      Y[(size_t)gm * N + gn] = val;
    }
  }
}

// ---------------- MFMA dense GEMM (+optional bf16 mirror, +optional BN stats)
template<int OUT_BF16, int DO_STATS>
__global__ __launch_bounds__(256) void mfma_gemm_kernel(
    const u16* __restrict__ Ab, const u16* __restrict__ WT,
    const float* __restrict__ bias, void* __restrict__ Y,
    u16* __restrict__ Ymirror, float* __restrict__ cs, float* __restrict__ cs2,
    int M, int K, int N) {
  const int tid = threadIdx.x;
  const int w = tid >> 6, l = tid & 63;
  const int lq = l >> 4, ln = l & 15;
  const int bm = blockIdx.y * 128, bn = blockIdx.x * 64;
  int ra = bm + w * 32 + ln;      if (ra > M - 1) ra = M - 1;
  int rb = bm + w * 32 + 16 + ln; if (rb > M - 1) rb = M - 1;
  f32x4 acc[2][4];
#pragma unroll
  for (int g = 0; g < 2; ++g)
#pragma unroll
    for (int nt = 0; nt < 4; ++nt) acc[g][nt] = {0.f, 0.f, 0.f, 0.f};
  for (int k0 = 0; k0 < K; k0 += 32) {
    bf16x8 a0 = *(const bf16x8*)&Ab[(size_t)ra * K + k0 + lq * 8];
    bf16x8 a1 = *(const bf16x8*)&Ab[(size_t)rb * K + k0 + lq * 8];
#pragma unroll
    for (int nt = 0; nt < 4; ++nt) {
      bf16x8 b = *(const bf16x8*)&WT[(size_t)(bn + nt * 16 + ln) * K + k0 + lq * 8];
      acc[0][nt] = __builtin_amdgcn_mfma_f32_16x16x32_bf16(a0, b, acc[0][nt], 0, 0, 0);
      acc[1][nt] = __builtin_amdgcn_mfma_f32_16x16x32_bf16(a1, b, acc[1][nt], 0, 0, 0);
    }
  }
#pragma unroll
  for (int g = 0; g < 2; ++g) {
    int rowbase = bm + w * 32 + g * 16 + lq * 4;
#pragma unroll
    for (int nt = 0; nt < 4; ++nt) {
      int gn = bn + nt * 16 + ln;
      float bv = bias ? bias[gn] : 0.f;
#pragma unroll
      for (int r = 0; r < 4; ++r) {
        int gm = rowbase + r;
        if (gm < M) {
          float val = acc[g][nt][r] + bv;
          if (OUT_BF16) ((u16*)Y)[(size_t)gm * N + gn] = f2bf(val);
          else          ((float*)Y)[(size_t)gm * N + gn] = val;
          if (Ymirror)  Ymirror[(size_t)gm * N + gn] = f2bf(val);
        }
      }
    }
  }
  if (DO_STATS) {
#pragma unroll
    for (int nt = 0; nt < 4; ++nt) {
      int gn = bn + nt * 16 + ln;
      float bv = bias ? bias[gn] : 0.f;
      float s = 0.f, s2 = 0.f;
#pragma unroll
      for (int g = 0; g < 2; ++g) {
        int rowbase = bm + w * 32 + g * 16 + lq * 4;
#pragma unroll
        for (int r = 0; r < 4; ++r) {
          if (rowbase + r < M) {
            float v = acc[g][nt][r] + bv;
            s += v; s2 += v * v;
          }
        }
      }
      s += __shfl_xor(s, 16); s2 += __shfl_xor(s2, 16);
      s += __shfl_xor(s, 32); s2 += __shfl_xor(s2, 32);
      if (lq == 0) { atomicAdd(&cs[gn], s); atomicAdd(&cs2[gn], s2); }
    }
  }
}

// ---------------- counting sort of edges by dst ------------------------------
__global__ void hist_kernel(const int* __restrict__ ei, int* __restrict__ cnt, int E) {
  int idx = blockIdx.x * blockDim.x + threadIdx.x;
  if (idx < E) atomicAdd(&cnt[ei[E + idx]], 1);
}

__global__ __launch_bounds__(256) void scan_kernel(const int* __restrict__ cnt,
                                                   int* __restrict__ offs) {
  __shared__ int wsum[4];
  __shared__ int carry_s;
  int tid = threadIdx.x, lane = tid & 63, w = tid >> 6;
  if (tid == 0) carry_s = 0;
  __syncthreads();
  for (int base = 0; base < N_NODES; base += 256) {
    int v = (base + tid < N_NODES) ? cnt[base + tid] : 0;
    int incl = v;
#pragma unroll
    for (int off = 1; off < 64; off <<= 1) {
      int t = __shfl_up(incl, off);
      if (lane >= off) incl += t;
    }
    if (lane == 63) wsum[w] = incl;
    __syncthreads();
    int woff = 0;
    for (int i = 0; i < w; ++i) woff += wsum[i];
    int carry = carry_s;
    if (base + tid < N_NODES) offs[base + tid] = carry + woff + incl - v;
    __syncthreads();
    if (tid == 0) carry_s = carry + wsum[0] + wsum[1] + wsum[2] + wsum[3];
    __syncthreads();
  }
}

__global__ void scatter_kernel(const int* __restrict__ ei, int* __restrict__ offs,
                               int* __restrict__ perm, int E) {
  int idx = blockIdx.x * blockDim.x + threadIdx.x;
  if (idx < E) {
    int d = ei[E + idx];
    int pos = atomicAdd(&offs[d], 1);
    perm[pos] = idx;
  }
}

// ---------------- init packs: xpad/epad/atomWT/WeT2 (z-sliced) ---------------
__global__ void pack_init_kernel(
    const float* __restrict__ x, const float* __restrict__ ea,
    const float* __restrict__ atom_W, const float* __restrict__ edge_W,
    u16* __restrict__ xpad, u16* __restrict__ epad,
    u16* __restrict__ atomWT, u16* __restrict__ WeT2) {
  int z = blockIdx.y;
  int idx0 = blockIdx.x * 256 + threadIdx.x;
  const int stride = 256 * 256;
  if (z == 0) {
    for (int idx = idx0; idx < N_NODES * 96; idx += stride) {
      int n = idx / 96, k = idx - n * 96;
      xpad[idx] = (k < 92) ? f2bf(x[(size_t)n * 92 + k]) : (u16)0;
    }
  } else if (z == 1) {
    for (int idx = idx0; idx < N_EDGES * 64; idx += stride) {
      int e = idx >> 6, k = idx & 63;
      epad[idx] = (k < 50) ? f2bf(ea[(size_t)e * 50 + k]) : (u16)0;
    }
  } else if (z == 2) {
    if (idx0 < 128 * 96) { int n = idx0 / 96, k = idx0 - n * 96;
      atomWT[idx0] = (k < 92) ? f2bf(atom_W[(size_t)k * 128 + n]) : (u16)0; }
  } else {
    if (idx0 < 128 * 64) { int n = idx0 >> 6, k = idx0 & 63;
      WeT2[idx0] = (k < 50) ? f2bf(edge_W[(size_t)k * 128 + n]) : (u16)0; }
  }
}

// ---------------- weight composition (fp32) ----------------------------------
__global__ __launch_bounds__(256) void compose_kernel(
    const float* __restrict__ Wv, const float* __restrict__ We,
    const float* __restrict__ Wmu, float* __restrict__ WP12,
    float* __restrict__ WPe) {
  const int z = blockIdx.z;
  const float* Ap; const float* Bp; float* Cp; int ldc;
  if (z < 4) {
    int part = z >> 1, h = z & 1;
    Ap = Wv + h * 128; Bp = Wmu + part * 128 * 384;
    Cp = WP12 + part * 768 + h * 384; ldc = 1536;
  } else {
    int h = z - 4;
    Ap = We + h * 128; Bp = Wmu + 256 * 384;
    Cp = WPe + h * 384; ldc = 768;
  }
  __shared__ float As[16][68];
  __shared__ float Bs[16][65];
  const int tid = threadIdx.x;
  const int bm = blockIdx.y * 64, bn = blockIdx.x * 64;
  const int tx = tid & 15, ty = tid >> 4;
  float acc[4][4] = {};
  for (int k0 = 0; k0 < 128; k0 += 16) {
#pragma unroll
    for (int i = 0; i < 4; ++i) {
      int l = tid + i * 256;
      int kk = l & 15, m = l >> 4;
      As[kk][m] = Ap[(size_t)(bm + m) * 256 + k0 + kk];
    }
#pragma unroll
    for (int i = 0; i < 4; ++i) {
      int l = tid + i * 256;
      int n = l & 63, kk = l >> 6;
      Bs[kk][n] = Bp[(size_t)(k0 + kk) * 384 + bn + n];
    }
    __syncthreads();
#pragma unroll
    for (int kk = 0; kk < 16; ++kk) {
      float a[4], b[4];
#pragma unroll
      for (int i = 0; i < 4; ++i) a[i] = As[kk][ty * 4 + i];
#pragma unroll
      for (int j = 0; j < 4; ++j) b[j] = Bs[kk][tx * 4 + j];
#pragma unroll
      for (int i = 0; i < 4; ++i)
#pragma unroll
        for (int j = 0; j < 4; ++j) acc[i][j] += a[i] * b[j];
    }
    __syncthreads();
  }
#pragma unroll
  for (int i = 0; i < 4; ++i)
#pragma unroll
    for (int j = 0; j < 4; ++j)
      Cp[(size_t)(bm + ty * 4 + i) * ldc + bn + tx * 4 + j] = acc[i][j];
}

// ---------------- merged pack kernels (z-sliced) -----------------------------
// z0: Wq->WallT[0:256]  z1: Wk->WallT[256:512]  z2: WcTw  z3: WskT  z4: WmTb
// z5: cbv  z6: ball  z7: zero agg + colsum/colsum2
__global__ void pack_all_kernel(
    const float* __restrict__ Wq, const float* __restrict__ Wk,
    const float* __restrict__ Wc, const float* __restrict__ Wsk,
    const float* __restrict__ Wm_l, const float* __restrict__ bmu,
    const float* __restrict__ bv_l, const float* __restrict__ Wmu,
    const float* __restrict__ bq_l, const float* __restrict__ bk_l,
    u16* __restrict__ WallT, u16* __restrict__ WcTw, u16* __restrict__ WskT,
    u16* __restrict__ WmTb, float* __restrict__ cbv, float* __restrict__ ball,
    float* __restrict__ agg, float* __restrict__ cs, float* __restrict__ cs2) {
  int z = blockIdx.y;
  int idx = blockIdx.x * 256 + threadIdx.x;
  if (z == 0) {
    if (idx < 32768) { int col = idx >> 7, kk = idx & 127;
      WallT[(size_t)col * 128 + kk] = f2bf(Wq[(size_t)kk * 256 + col]); }
  } else if (z == 1) {
    if (idx < 32768) { int col = idx >> 7, kk = idx & 127;
      WallT[(size_t)(256 + col) * 128 + kk] = f2bf(Wk[(size_t)kk * 256 + col]); }
  } else if (z == 2) {
    if (idx < 32768) { int col = idx >> 8, kk = idx & 255;
      WcTw[(size_t)col * 256 + kk] = f2bf(Wc[(size_t)kk * 128 + col]); }
  } else if (z == 3) {
    if (idx < 16384) { int col = idx >> 7, kk = idx & 127;
      WskT[(size_t)col * 128 + kk] = f2bf(Wsk[(size_t)kk * 128 + col]); }
  } else if (z == 4) {
    if (idx < 49152) { int col = idx / 384, kk = idx - col * 384;
      WmTb[idx] = f2bf(Wm_l[(size_t)kk * 128 + col]); }
  } else if (z == 5) {
    if (idx < 768) {
      int h2 = idx / 384, g = idx - h2 * 384;
      float s = bmu[g];
      for (int d = 0; d < 128; ++d)
        s += bv_l[h2 * 128 + d] * (Wmu[(size_t)d * 384 + g] + Wmu[(size_t)(128 + d) * 384 + g]);
      cbv[idx] = s;
    }
  } else if (z == 6) {
    if (idx < 2048) {
      float v = 0.f;
      if (idx < 256) v = bq_l[idx];
      else if (idx < 512) v = bk_l[idx - 256];
      ball[idx] = v;
    }
  } else {
    for (int p = idx; p < N_NODES * HCDIM; p += 192 * 256) agg[p] = 0.f;
    if (idx < 128) { cs[idx] = 0.f; cs2[idx] = 0.f; }
  }
}

// z0: [We|WPe] -> WcT   z1: WP12 -> WallT[512:2048]
__global__ void packcomb_kernel(const float* __restrict__ We_l,
                                const float* __restrict__ WPe,
                                const float* __restrict__ WP12,
                                u16* __restrict__ WcT, u16* __restrict__ WallT) {
  int z = blockIdx.y;
  int idx = blockIdx.x * 256 + threadIdx.x;
  if (z == 0) {
    if (idx < 131072) { int col = idx >> 7, kk = idx & 127;
      float v = (col < 256) ? We_l[(size_t)kk * 256 + col]
                            : WPe[(size_t)kk * 768 + (col - 256)];
      WcT[idx] = f2bf(v); }
  } else {
    if (idx < 196608) { int col = idx >> 7, kk = idx & 127;
      WallT[(size_t)(512 + col) * 128 + kk] = f2bf(WP12[(size_t)kk * 1536 + col]); }
  }
}

__global__ void pack_bf16_kernel(const float* __restrict__ A, u16* __restrict__ B, int n) {
  int idx = blockIdx.x * blockDim.x + threadIdx.x;
  if (idx < n) B[idx] = f2bf(A[idx]);
}

// ---------------- fused per-edge kernel (MFMA, 16 sorted edges/block) --------
__global__ __launch_bounds__(256, 3) void edge_kernel(
    const u16* __restrict__ qkp, const u16* __restrict__ efb,
    const int* __restrict__ ei, const int* __restrict__ perm,
    const u16* __restrict__ WcT, const float* __restrict__ cbv,
    const float* __restrict__ lag, const float* __restrict__ lab,
    const u16* __restrict__ WmT, const float* __restrict__ bm_l,
    const float* __restrict__ lmg, const float* __restrict__ lmb,
    float* __restrict__ agg, int E) {
  __shared__ __align__(16) u16 C1[16 * 1032];
  __shared__ __align__(16) u16 A2p[12 * 512];   // aliased as C2 float[16][132]
  __shared__ int did16[16];
  float* C2 = (float*)A2p;
  const int tid = threadIdx.x;
  const int e0 = blockIdx.x * 16;
  const int w = tid >> 6, l = tid & 63;
  const int lq = l >> 4, ln = l & 15;
  const float scale = 0.051031036307982884f;  // 1/sqrt(384)

  if (tid < 16) { int e = perm[e0 + tid]; did16[tid] = ei[E + e]; }

  // thread mapping for Phase A+4: row r = hA*8+eA, 16 lanes lx per row
  const int r = tid >> 4, lx = tid & 15;
  const int hA = r >> 3, eA = r & 7;

  // ---- Prefetch gathers for both sub-batches (sorted edge ids via perm) ----
  bf16x8 qv[2], kdv[2], ksv[2], pdv[2][3], psv[2][3];
#pragma unroll
  for (int s = 0; s < 2; ++s) {
    int e = perm[e0 + s * 8 + eA];
    int dstn = ei[E + e], srcn = ei[e];
    const u16* db = qkp + (size_t)dstn * 2048;
    const u16* sb = qkp + (size_t)srcn * 2048;
    qv[s]  = *(const bf16x8*)&db[hA * 128 + lx * 8];
    kdv[s] = *(const bf16x8*)&db[256 + hA * 128 + lx * 8];
    ksv[s] = *(const bf16x8*)&sb[256 + hA * 128 + lx * 8];
#pragma unroll
    for (int p = 0; p < 3; ++p) {
      pdv[s][p] = *(const bf16x8*)&db[512 + hA * 384 + p * 128 + lx * 8];
      psv[s][p] = *(const bf16x8*)&sb[512 + 768 + hA * 384 + p * 128 + lx * 8];
    }
  }

  // ---- GEMM1: C1[16][1024] = efb[perm rows] @ WcT ----
  {
    int er = perm[e0 + ln];
    bf16x8 afr[4];
    const u16* ab = efb + (size_t)er * 128 + lq * 8;
#pragma unroll
    for (int ks = 0; ks < 4; ++ks) afr[ks] = *(const bf16x8*)(ab + ks * 32);
    for (int nt = 0; nt < 16; ++nt) {
      int g = w * 16 + nt;
      const u16* bb = WcT + (size_t)(g * 16 + ln) * 128 + lq * 8;
      f32x4 acc = {0.f, 0.f, 0.f, 0.f};
#pragma unroll
      for (int ks = 0; ks < 4; ++ks)
        acc = __builtin_amdgcn_mfma_f32_16x16x32_bf16(
            afr[ks], *(const bf16x8*)(bb + ks * 32), acc, 0, 0, 0);
      int col = g * 16 + ln;
#pragma unroll
      for (int rr = 0; rr < 4; ++rr) C1[(lq * 4 + rr) * 1032 + col] = f2bf(acc[rr]);
    }
  }
  __syncthreads();

  // scatter-aggregation state (persists across both sub-batches)
  float agg0 = 0.f, agg1 = 0.f;
  int cur = -1;
  const int hW = w >> 1;

  for (int s = 0; s < 2; ++s) {
    // ---- Phase A+4 fused: alpha -> LN384 -> gate (regs) -> t -> A2p ----
    {
      bf16x8 sea = *(const bf16x8*)&C1[(s * 8 + eA) * 1032 + hA * 128 + lx * 8];
      float a0[8], a1[8], a2[8];
      float sacc = 0.f, s2acc = 0.f;
#pragma unroll
      for (int j = 0; j < 8; ++j) {
        float qf = bf2f((u16)qv[s][j]);
        float x0 = qf * bf2f((u16)kdv[s][j]) * scale;
        float x1 = qf * bf2f((u16)ksv[s][j]) * scale;
        float x2 = qf * bf2f((u16)sea[j]) * scale;
        a0[j] = x0; a1[j] = x1; a2[j] = x2;
        sacc += x0 + x1 + x2;
        s2acc += x0 * x0 + x1 * x1 + x2 * x2;
      }
#pragma unroll
      for (int mm = 1; mm < 16; mm <<= 1) {
        sacc += __shfl_xor(sacc, mm); s2acc += __shfl_xor(s2acc, mm);
      }
      float mean = sacc * (1.f / C3DIM);
      float rstd = rsqrtf(s2acc * (1.f / C3DIM) - mean * mean + 1e-5f);
#pragma unroll
      for (int p = 0; p < 3; ++p) {
        const float* lg = lag + p * 128 + lx * 8;
        const float* lb = lab + p * 128 + lx * 8;
        f32x4 g0 = *(const f32x4*)lg, g1 = *(const f32x4*)(lg + 4);
        f32x4 b0 = *(const f32x4*)lb, b1 = *(const f32x4*)(lb + 4);
        f32x4 c0 = *(const f32x4*)&cbv[hA * 384 + p * 128 + lx * 8];
        f32x4 c1 = *(const f32x4*)&cbv[hA * 384 + p * 128 + lx * 8 + 4];
        bf16x8 pe = *(const bf16x8*)&C1[(s * 8 + eA) * 1032 + 256 + hA * 384 + p * 128 + lx * 8];
        bf16x8 outv;
#pragma unroll
        for (int j = 0; j < 8; ++j) {
          float av = p == 0 ? a0[j] : (p == 1 ? a1[j] : a2[j]);
          float gg = j < 4 ? g0[j] : g1[j - 4];
          float bb2 = j < 4 ? b0[j] : b1[j - 4];
          float cbj = j < 4 ? c0[j] : c1[j - 4];
          float z = (av - mean) * rstd * gg + bb2;
          float gate = 1.f / (1.f + expf(-z));
          float t = (bf2f((u16)pe[j]) + bf2f((u16)pdv[s][p][j]) +
                     bf2f((u16)psv[s][p][j]) + cbj) * gate;
          outv[j] = (short)f2bf(t);
        }
        int ks = p * 4 + (lx >> 2), qq = lx & 3;
        int slot = (((r ^ (qq << 2)) + ks) & 15) | (qq << 4);
        *(bf16x8*)&A2p[ks * 512 + slot * 8] = outv;
      }
    }
    __syncthreads();

    // ---- GEMM2: load A2 frags (swizzled), barrier, MFMA, write C2 (aliased) -
    {
      bf16x8 af2[12];
#pragma unroll
      for (int ks = 0; ks < 12; ++ks) {
        int slot = (((ln ^ (lq << 2)) + ks) & 15) | (lq << 4);
        af2[ks] = *(const bf16x8*)&A2p[ks * 512 + slot * 8];
      }
      __syncthreads();  // all reads of A2p complete before aliased C2 writes
#pragma unroll
      for (int nt = 0; nt < 2; ++nt) {
        int g = w * 2 + nt;
        const u16* bb = WmT + (size_t)(g * 16 + ln) * 384 + lq * 8;
        f32x4 acc = {0.f, 0.f, 0.f, 0.f};
#pragma unroll
        for (int ks = 0; ks < 12; ++ks)
          acc = __builtin_amdgcn_mfma_f32_16x16x32_bf16(
              af2[ks], *(const bf16x8*)(bb + ks * 32), acc, 0, 0, 0);
        int col = g * 16 + ln;
        float bcol = bm_l[col];
#pragma unroll
        for (int rr = 0; rr < 4; ++rr) C2[(lq * 4 + rr) * 132 + col] = acc[rr] + bcol;
      }
    }
    __syncthreads();

    // ---- LN128 + run-aggregated scatter (wave w: rows w*4..w*4+3, head hW) --
    {
#pragma unroll
      for (int i = 0; i < 4; ++i) {
        int rw = w * 4 + i;
        int e = rw & 7;
        float v0 = C2[rw * 132 + l], v1 = C2[rw * 132 + l + 64];
        float sa = v0 + v1, s2a = v0 * v0 + v1 * v1;
#pragma unroll
        for (int off2 = 32; off2 > 0; off2 >>= 1) {
          sa += __shfl_down(sa, off2); s2a += __shfl_down(s2a, off2);
        }
        sa = __shfl(sa, 0); s2a = __shfl(s2a, 0);
        float mean = sa * (1.f / CDIM);
        float rstd = rsqrtf(s2a * (1.f / CDIM) - mean * mean + 1e-5f);
        float o0 = (v0 - mean) * rstd * lmg[l] + lmb[l];
        float o1 = (v1 - mean) * rstd * lmg[l + 64] + lmb[l + 64];
        int dstn = did16[s * 8 + e];
        if (dstn != cur) {
          if (cur >= 0) {
            atomicAdd(&agg[(size_t)cur * HCDIM + hW * CDIM + l], agg0);
            atomicAdd(&agg[(size_t)cur * HCDIM + hW * CDIM + l + 64], agg1);
          }
          cur = dstn; agg0 = o0; agg1 = o1;
        } else { agg0 += o0; agg1 += o1; }
      }
    }
    __syncthreads();
  }
  if (cur >= 0) {
    atomicAdd(&agg[(size_t)cur * HCDIM + hW * CDIM + l], agg0);
    atomicAdd(&agg[(size_t)cur * HCDIM + hW * CDIM + l + 64], agg1);
  }
}

// ---------------- fused BN(from sums) + SiLU + skip (+psum zero) -------------
__global__ void bn_silu_skip_kernel(
    const float* __restrict__ o, const float* __restrict__ skip,
    const float* __restrict__ cs, const float* __restrict__ cs2,
    const float* __restrict__ g, const float* __restrict__ b,
    float* __restrict__ nf, u16* __restrict__ nfb, float* __restrict__ pz) {
  int idx = blockIdx.x * blockDim.x + threadIdx.x;
  if (idx >= N_NODES * CDIM) return;
  int c = idx & (CDIM - 1);
  float m = cs[c] * (1.f / N_NODES);
  float var = cs2[c] * (1.f / N_NODES) - m * m;
  float rstd = rsqrtf(var + 1e-5f);
  float x = (o[idx] - m) * rstd * g[c] + b[c];
  float sig = 1.f / (1.f + expf(-x));
  float val = x * sig + skip[idx];
  nf[idx] = val;
  nfb[idx] = f2bf(val);
  if (pz && idx < N_GRAPH * CDIM + N_GRAPH) pz[idx] = 0.f;
}

__global__ void pool_kernel(const float* __restrict__ nf, const int* __restrict__ batch,
                            float* __restrict__ psum, float* __restrict__ cnt) {
  int idx = blockIdx.x * blockDim.x + threadIdx.x;
  if (idx >= N_NODES * CDIM) return;
  int n = idx >> 7, c = idx & 127;
  int b = batch[n];
  atomicAdd(&psum[b * CDIM + c], nf[idx]);
  if (c == 0) atomicAdd(&cnt[b], 1.f);
}

__global__ void feats_kernel(const float* __restrict__ psum, const float* __restrict__ cnt,
                             const float* __restrict__ pge, const float* __restrict__ cse,
                             float* __restrict__ feats) {
  int idx = blockIdx.x * blockDim.x + threadIdx.x;
  if (idx >= N_GRAPH * 167) return;
  int b = idx / 167, j = idx - b * 167;
  float val;
  if (j < 128)      val = psum[b * CDIM + j] / fmaxf(cnt[b], 1.f);
  else if (j < 160) val = pge[b * 32 + (j - 128)];
  else              val = cse[b * 7 + (j - 160)];
  feats[idx] = val;
}

__global__ __launch_bounds__(256) void out_kernel(
    const float* __restrict__ h, const float* __restrict__ ow,
    const float* __restrict__ ob, float* __restrict__ out) {
  int b = blockIdx.x, tid = threadIdx.x;
  float s = h[b * 512 + tid] * ow[tid] + h[b * 512 + tid + 256] * ow[tid + 256];
  __shared__ float red[4];
#pragma unroll
  for (int off = 32; off > 0; off >>= 1) s += __shfl_down(s, off);
  if ((tid & 63) == 0) red[tid >> 6] = s;
  __syncthreads();
  if (tid == 0) out[b] = red[0] + red[1] + red[2] + red[3] + ob[0];
}

// ---------------- launch -----------------------------------------------------
extern "C" void kernel_launch(void* const* d_in, const int* in_sizes, int n_in,
                              void* d_out, int out_size, void* d_ws, size_t ws_size,
                              hipStream_t stream) {
  const float* x         = (const float*)d_in[0];
  const float* edge_attr = (const float*)d_in[1];
  const float* pge       = (const float*)d_in[2];
  const float* cse       = (const float*)d_in[3];
  const int*   ei        = (const int*)d_in[4];
  const int*   batch     = (const int*)d_in[5];
  const float* atom_W    = (const float*)d_in[6];
  const float* atom_b    = (const float*)d_in[7];
  const float* edge_W    = (const float*)d_in[8];
  const float* edge_b    = (const float*)d_in[9];
  const float* Wq        = (const float*)d_in[10];
  const float* bq        = (const float*)d_in[11];
  const float* Wk        = (const float*)d_in[12];
  const float* bk        = (const float*)d_in[13];
  const float* Wv        = (const float*)d_in[14];
  const float* bv        = (const float*)d_in[15];
  const float* We        = (const float*)d_in[16];
  const float* Wmu       = (const float*)d_in[17];
  const float* bmu       = (const float*)d_in[18];
  const float* Wm        = (const float*)d_in[19];
  const float* bm        = (const float*)d_in[20];
  const float* ln_m_g    = (const float*)d_in[21];
  const float* ln_m_b    = (const float*)d_in[22];
  const float* ln_a_g    = (const float*)d_in[23];
  const float* ln_a_b    = (const float*)d_in[24];
  const float* Wc        = (const float*)d_in[25];
  const float* bc        = (const float*)d_in[26];
  const float* bn_g      = (const float*)d_in[27];
  const float* bn_b      = (const float*)d_in[28];
  const float* Wskip     = (const float*)d_in[29];
  const float* bskip     = (const float*)d_in[30];
  const float* fc_W      = (const float*)d_in[31];
  const float* fc_b      = (const float*)d_in[32];
  const float* out_W     = (const float*)d_in[33];
  const float* out_b     = (const float*)d_in[34];

  float* ws = (float*)d_ws;
  size_t off = 0;
  float* nf    = ws + off; off += (size_t)N_NODES * CDIM;
  float* agg   = ws + off; off += (size_t)N_NODES * HCDIM;
  float* o     = ws + off; off += (size_t)N_NODES * CDIM;
  float* skip  = ws + off; off += (size_t)N_NODES * CDIM;
  float* WP12  = ws + off; off += (size_t)128 * 1536;
  float* WPe   = ws + off; off += (size_t)128 * 768;
  float* cbv   = ws + off; off += 768;
  float* ball  = ws + off; off += 2048;
  float* csum  = ws + off; off += CDIM;
  float* csum2 = ws + off; off += CDIM;
  float* psum  = ws + off; off += (size_t)N_GRAPH * CDIM;
  float* cnt   = ws + off; off += N_GRAPH;
  float* feats = ws + off; off += (size_t)N_GRAPH * 167;
  float* h     = ws + off; off += (size_t)N_GRAPH * 512;
  int* scnt    = (int*)(ws + off); off += N_NODES;
  int* soffs   = (int*)(ws + off); off += N_NODES;
  int* perm    = (int*)(ws + off); off += N_EDGES;
  u16* efb   = (u16*)(ws + off); off += (size_t)N_EDGES * 64;     // E*128 u16
  u16* WcT   = (u16*)(ws + off); off += 65536;                    // 1024*128 u16
  u16* WmTb  = (u16*)(ws + off); off += 24576;                    // 128*384 u16
  u16* nfb   = (u16*)(ws + off); off += (size_t)N_NODES * 64;     // N*128 u16
  u16* aggb  = (u16*)(ws + off); off += (size_t)N_NODES * 128;    // N*256 u16
  u16* qkp   = (u16*)(ws + off); off += (size_t)N_NODES * 1024;   // N*2048 u16
  u16* WallT = (u16*)(ws + off); off += 131072;                   // 2048*128 u16
  u16* WcTw  = (u16*)(ws + off); off += 16384;                    // 128*256 u16
  u16* WskT  = (u16*)(ws + off); off += 8192;                     // 128*128 u16
  u16* xpad  = (u16*)(ws + off); off += (size_t)N_NODES * 48;     // N*96 u16
  u16* epad  = (u16*)(ws + off); off += (size_t)N_EDGES * 32;     // E*64 u16
  u16* atomWT= (u16*)(ws + off); off += 6144;                     // 128*96 u16
  u16* WeT2  = (u16*)(ws + off); off += 4096;                     // 128*64 u16

  // ---- one-time: sort edges by dst, pack inputs, initial MFMA GEMMs ----
  hipMemsetAsync(scnt, 0, N_NODES * sizeof(int), stream);
  hist_kernel<<<dim3((N_EDGES + 255) / 256), 256, 0, stream>>>(ei, scnt, N_EDGES);
  scan_kernel<<<dim3(1), 256, 0, stream>>>(scnt, soffs);
  scatter_kernel<<<dim3((N_EDGES + 255) / 256), 256, 0, stream>>>(ei, soffs, perm, N_EDGES);
  pack_init_kernel<<<dim3(256, 4), 256, 0, stream>>>(x, edge_attr, atom_W, edge_W,
                                                     xpad, epad, atomWT, WeT2);
  mfma_gemm_kernel<0, 0><<<dim3(2, 79), 256, 0, stream>>>(
      xpad, atomWT, atom_b, nf, nfb, nullptr, nullptr, N_NODES, 96, CDIM);
  mfma_gemm_kernel<1, 0><<<dim3(2, 782), 256, 0, stream>>>(
      epad, WeT2, edge_b, efb, nullptr, nullptr, nullptr, N_EDGES, 64, CDIM);

  for (int i = 0; i < 2; ++i) {
    const float* Wv_i  = Wv + (size_t)i * CDIM * HCDIM;
    const float* We_i  = We + (size_t)i * CDIM * HCDIM;
    const float* Wmu_i = Wmu + (size_t)i * C3DIM * C3DIM;
    compose_kernel<<<dim3(6, 2, 6), 256, 0, stream>>>(Wv_i, We_i, Wmu_i, WP12, WPe);
    pack_all_kernel<<<dim3(192, 8), 256, 0, stream>>>(
        Wq + (size_t)i * CDIM * HCDIM, Wk + (size_t)i * CDIM * HCDIM,
        Wc + (size_t)i * HCDIM * CDIM, Wskip + (size_t)i * CDIM * CDIM,
        Wm + (size_t)i * C3DIM * CDIM, bmu + i * C3DIM, bv + i * HCDIM, Wmu_i,
        bq + i * HCDIM, bk + i * HCDIM,
        WallT, WcTw, WskT, WmTb, cbv, ball, agg, csum, csum2);
    packcomb_kernel<<<dim3(768, 2), 256, 0, stream>>>(We_i, WPe, WP12, WcT, WallT);

    // qkp = nfb @ [Wq|Wk|WP12]  (N=2048, bf16 out)
    mfma_gemm_kernel<1, 0><<<dim3(32, 79), 256, 0, stream>>>(
        nfb, WallT, ball, qkp, nullptr, nullptr, nullptr, N_NODES, CDIM, 2048);

    edge_kernel<<<dim3(N_EDGES / 16), dim3(256), 0, stream>>>(
        qkp, efb, ei, perm, WcT, cbv,
        ln_a_g + i * C3DIM, ln_a_b + i * C3DIM,
        WmTb, bm + i * CDIM,
        ln_m_g + i * CDIM, ln_m_b + i * CDIM, agg, N_EDGES);

    pack_bf16_kernel<<<dim3((N_NODES * 256 + 255) / 256), dim3(256), 0, stream>>>(
        agg, aggb, N_NODES * 256);
    mfma_gemm_kernel<0, 1><<<dim3(2, 79), 256, 0, stream>>>(
        aggb, WcTw, bc + i * CDIM, o, nullptr, csum, csum2, N_NODES, HCDIM, CDIM);
    mfma_gemm_kernel<0, 0><<<dim3(2, 79), 256, 0, stream>>>(
        nfb, WskT, bskip + i * CDIM, skip, nullptr, nullptr, nullptr, N_NODES, CDIM, CDIM);
    bn_silu_skip_kernel<<<dim3((N_NODES * CDIM + 255) / 256), dim3(256), 0, stream>>>(
        o, skip, csum, csum2, bn_g + i * CDIM, bn_b + i * CDIM, nf, nfb,
        (i == 1) ? psum : nullptr);
  }

  pool_kernel<<<dim3((N_NODES * CDIM + 255) / 256), dim3(256), 0, stream>>>(nf, batch, psum, cnt);
  feats_kernel<<<dim3((N_GRAPH * 167 + 255) / 256), dim3(256), 0, stream>>>(psum, cnt, pge, cse, feats);
  gemm_kernel<1><<<dim3(8, 1), 256, 0, stream>>>(feats, fc_W, fc_b, h, N_GRAPH, 167, 512);
  out_kernel<<<dim3(N_GRAPH), 256, 0, stream>>>(h, out_W, out_b, (float*)d_out);
}

// Round 8
// 1244.761 us; speedup vs baseline: 1.5438x; 1.5438x over previous
//
#include <hip/hip_runtime.h>
#include <math.h>

#define N_NODES 10000
#define N_EDGES 100000
#define N_GRAPH 64
#define CDIM 128
#define HCDIM 256
#define C3DIM 384

typedef unsigned short u16;
typedef __attribute__((ext_vector_type(8))) short bf16x8;
typedef __attribute__((ext_vector_type(4))) float f32x4;

__device__ __forceinline__ u16 f2bf(float f) {
  union { float f; unsigned int u; } x; x.f = f;
  unsigned int u = x.u + 0x7fffu + ((x.u >> 16) & 1u);
  return (u16)(u >> 16);
}
__device__ __forceinline__ float bf2f(u16 h) {
  union { unsigned int u; float f; } x; x.u = ((unsigned int)h) << 16;
  return x.f;
}

// ---------------- MFMA dense GEMM (+optional bf16 mirror, +optional BN stats)
template<int OUT_BF16, int DO_STATS>
__global__ __launch_bounds__(256) void mfma_gemm_kernel(
    const u16* __restrict__ Ab, const u16* __restrict__ WT,
    const float* __restrict__ bias, void* __restrict__ Y,
    u16* __restrict__ Ymirror, float* __restrict__ cs, float* __restrict__ cs2,
    int M, int K, int N) {
  const int tid = threadIdx.x;
  const int w = tid >> 6, l = tid & 63;
  const int lq = l >> 4, ln = l & 15;
  const int bm = blockIdx.y * 128, bn = blockIdx.x * 64;
  int ra = bm + w * 32 + ln;      if (ra > M - 1) ra = M - 1;
  int rb = bm + w * 32 + 16 + ln; if (rb > M - 1) rb = M - 1;
  f32x4 acc[2][4];
#pragma unroll
  for (int g = 0; g < 2; ++g)
#pragma unroll
    for (int nt = 0; nt < 4; ++nt) acc[g][nt] = {0.f, 0.f, 0.f, 0.f};
  for (int k0 = 0; k0 < K; k0 += 32) {
    bf16x8 a0 = *(const bf16x8*)&Ab[(size_t)ra * K + k0 + lq * 8];
    bf16x8 a1 = *(const bf16x8*)&Ab[(size_t)rb * K + k0 + lq * 8];
#pragma unroll
    for (int nt = 0; nt < 4; ++nt) {
      bf16x8 b = *(const bf16x8*)&WT[(size_t)(bn + nt * 16 + ln) * K + k0 + lq * 8];
      acc[0][nt] = __builtin_amdgcn_mfma_f32_16x16x32_bf16(a0, b, acc[0][nt], 0, 0, 0);
      acc[1][nt] = __builtin_amdgcn_mfma_f32_16x16x32_bf16(a1, b, acc[1][nt], 0, 0, 0);
    }
  }
#pragma unroll
  for (int g = 0; g < 2; ++g) {
    int rowbase = bm + w * 32 + g * 16 + lq * 4;
#pragma unroll
    for (int nt = 0; nt < 4; ++nt) {
      int gn = bn + nt * 16 + ln;
      float bv = bias ? bias[gn] : 0.f;
#pragma unroll
      for (int r = 0; r < 4; ++r) {
        int gm = rowbase + r;
        if (gm < M) {
          float val = acc[g][nt][r] + bv;
          if (OUT_BF16) ((u16*)Y)[(size_t)gm * N + gn] = f2bf(val);
          else          ((float*)Y)[(size_t)gm * N + gn] = val;
          if (Ymirror)  Ymirror[(size_t)gm * N + gn] = f2bf(val);
        }
      }
    }
  }
  if (DO_STATS) {
#pragma unroll
    for (int nt = 0; nt < 4; ++nt) {
      int gn = bn + nt * 16 + ln;
      float bv = bias ? bias[gn] : 0.f;
      float s = 0.f, s2 = 0.f;
#pragma unroll
      for (int g = 0; g < 2; ++g) {
        int rowbase = bm + w * 32 + g * 16 + lq * 4;
#pragma unroll
        for (int r = 0; r < 4; ++r) {
          if (rowbase + r < M) {
            float v = acc[g][nt][r] + bv;
            s += v; s2 += v * v;
          }
        }
      }
      s += __shfl_xor(s, 16); s2 += __shfl_xor(s2, 16);
      s += __shfl_xor(s, 32); s2 += __shfl_xor(s2, 32);
      if (lq == 0) { atomicAdd(&cs[gn], s); atomicAdd(&cs2[gn], s2); }
    }
  }
}

// ---------------- init packs: xpad/epad/atomWT/WeT2 (z-sliced) ---------------
__global__ void pack_init_kernel(
    const float* __restrict__ x, const float* __restrict__ ea,
    const float* __restrict__ atom_W, const float* __restrict__ edge_W,
    u16* __restrict__ xpad, u16* __restrict__ epad,
    u16* __restrict__ atomWT, u16* __restrict__ WeT2) {
  int z = blockIdx.y;
  int idx0 = blockIdx.x * 256 + threadIdx.x;
  const int stride = 256 * 256;
  if (z == 0) {
    for (int idx = idx0; idx < N_NODES * 96; idx += stride) {
      int n = idx / 96, k = idx - n * 96;
      xpad[idx] = (k < 92) ? f2bf(x[(size_t)n * 92 + k]) : (u16)0;
    }
  } else if (z == 1) {
    for (int idx = idx0; idx < N_EDGES * 64; idx += stride) {
      int e = idx >> 6, k = idx & 63;
      epad[idx] = (k < 50) ? f2bf(ea[(size_t)e * 50 + k]) : (u16)0;
    }
  } else if (z == 2) {
    if (idx0 < 128 * 96) { int n = idx0 / 96, k = idx0 - n * 96;
      atomWT[idx0] = (k < 92) ? f2bf(atom_W[(size_t)k * 128 + n]) : (u16)0; }
  } else {
    if (idx0 < 128 * 64) { int n = idx0 >> 6, k = idx0 & 63;
      WeT2[idx0] = (k < 50) ? f2bf(edge_W[(size_t)k * 128 + n]) : (u16)0; }
  }
}

// ---------------- weight composition -> bf16 direct --------------------------
// z<4:  WP12 part -> WallT[512 + col][k]   (col = part*768 + h*384 + g)
// z>=4: WPe  part -> WcT [256 + h*384 + g][k]
__global__ __launch_bounds__(256) void compose_kernel(
    const float* __restrict__ Wv, const float* __restrict__ We,
    const float* __restrict__ Wmu, u16* __restrict__ WallT,
    u16* __restrict__ WcT) {
  const int z = blockIdx.z;
  const float* Ap; const float* Bp;
  u16* Cp; int colbase;
  if (z < 4) {
    int part = z >> 1, h = z & 1;
    Ap = Wv + h * 128; Bp = Wmu + part * 128 * 384;
    Cp = WallT; colbase = 512 + part * 768 + h * 384;
  } else {
    int h = z - 4;
    Ap = We + h * 128; Bp = Wmu + 256 * 384;
    Cp = WcT; colbase = 256 + h * 384;
  }
  __shared__ float As[16][68];
  __shared__ float Bs[16][65];
  const int tid = threadIdx.x;
  const int bm = blockIdx.y * 64, bn = blockIdx.x * 64;
  const int tx = tid & 15, ty = tid >> 4;
  float acc[4][4] = {};
  for (int k0 = 0; k0 < 128; k0 += 16) {
#pragma unroll
    for (int i = 0; i < 4; ++i) {
      int l = tid + i * 256;
      int kk = l & 15, m = l >> 4;
      As[kk][m] = Ap[(size_t)(bm + m) * 256 + k0 + kk];
    }
#pragma unroll
    for (int i = 0; i < 4; ++i) {
      int l = tid + i * 256;
      int n = l & 63, kk = l >> 6;
      Bs[kk][n] = Bp[(size_t)(k0 + kk) * 384 + bn + n];
    }
    __syncthreads();
#pragma unroll
    for (int kk = 0; kk < 16; ++kk) {
      float a[4], b[4];
#pragma unroll
      for (int i = 0; i < 4; ++i) a[i] = As[kk][ty * 4 + i];
#pragma unroll
      for (int j = 0; j < 4; ++j) b[j] = Bs[kk][tx * 4 + j];
#pragma unroll
      for (int i = 0; i < 4; ++i)
#pragma unroll
        for (int j = 0; j < 4; ++j) acc[i][j] += a[i] * b[j];
    }
    __syncthreads();
  }
  // transposed bf16 write: [col][k]
#pragma unroll
  for (int i = 0; i < 4; ++i) {
    int gk = bm + ty * 4 + i;
#pragma unroll
    for (int j = 0; j < 4; ++j) {
      int gcol = colbase + bn + tx * 4 + j;
      Cp[(size_t)gcol * 128 + gk] = f2bf(acc[i][j]);
    }
  }
}

// ---------------- merged pack kernel (z-sliced) ------------------------------
// z0: Wq->WallT[0:256]  z1: Wk->WallT[256:512]  z2: WcTw  z3: WskT  z4: WmTb
// z5: cbv  z6: ball  z7: zero agg + colsum/colsum2  z8: We->WcT[0:256]
__global__ void pack_all_kernel(
    const float* __restrict__ Wq, const float* __restrict__ Wk,
    const float* __restrict__ Wc, const float* __restrict__ Wsk,
    const float* __restrict__ Wm_l, const float* __restrict__ bmu,
    const float* __restrict__ bv_l, const float* __restrict__ Wmu,
    const float* __restrict__ bq_l, const float* __restrict__ bk_l,
    const float* __restrict__ We_l,
    u16* __restrict__ WallT, u16* __restrict__ WcTw, u16* __restrict__ WskT,
    u16* __restrict__ WmTb, float* __restrict__ cbv, float* __restrict__ ball,
    float* __restrict__ agg, float* __restrict__ cs, float* __restrict__ cs2,
    u16* __restrict__ WcT) {
  int z = blockIdx.y;
  int idx = blockIdx.x * 256 + threadIdx.x;
  if (z == 0) {
    if (idx < 32768) { int col = idx >> 7, kk = idx & 127;
      WallT[(size_t)col * 128 + kk] = f2bf(Wq[(size_t)kk * 256 + col]); }
  } else if (z == 1) {
    if (idx < 32768) { int col = idx >> 7, kk = idx & 127;
      WallT[(size_t)(256 + col) * 128 + kk] = f2bf(Wk[(size_t)kk * 256 + col]); }
  } else if (z == 2) {
    if (idx < 32768) { int col = idx >> 8, kk = idx & 255;
      WcTw[(size_t)col * 256 + kk] = f2bf(Wc[(size_t)kk * 128 + col]); }
  } else if (z == 3) {
    if (idx < 16384) { int col = idx >> 7, kk = idx & 127;
      WskT[(size_t)col * 128 + kk] = f2bf(Wsk[(size_t)kk * 128 + col]); }
  } else if (z == 4) {
    if (idx < 49152) { int col = idx / 384, kk = idx - col * 384;
      WmTb[idx] = f2bf(Wm_l[(size_t)kk * 128 + col]); }
  } else if (z == 5) {
    if (idx < 768) {
      int h2 = idx / 384, g = idx - h2 * 384;
      float s = bmu[g];
      for (int d = 0; d < 128; ++d)
        s += bv_l[h2 * 128 + d] * (Wmu[(size_t)d * 384 + g] + Wmu[(size_t)(128 + d) * 384 + g]);
      cbv[idx] = s;
    }
  } else if (z == 6) {
    if (idx < 2048) {
      float v = 0.f;
      if (idx < 256) v = bq_l[idx];
      else if (idx < 512) v = bk_l[idx - 256];
      ball[idx] = v;
    }
  } else if (z == 7) {
    for (int p = idx; p < N_NODES * HCDIM; p += 192 * 256) agg[p] = 0.f;
    if (idx < 128) { cs[idx] = 0.f; cs2[idx] = 0.f; }
  } else {
    if (idx < 32768) { int col = idx >> 7, kk = idx & 127;
      WcT[(size_t)col * 128 + kk] = f2bf(We_l[(size_t)kk * 256 + col]); }
  }
}

__global__ void pack_bf16_kernel(const float* __restrict__ A, u16* __restrict__ B, int n) {
  int idx = blockIdx.x * blockDim.x + threadIdx.x;
  if (idx < n) B[idx] = f2bf(A[idx]);
}

// ---------------- fused per-edge kernel (MFMA, 16 edges/block) ---------------
// qkp row layout per node: [q(256) | k(256) | P12(1536)]  (2048 bf16)
__global__ __launch_bounds__(256, 3) void edge_kernel(
    const u16* __restrict__ qkp, const u16* __restrict__ efb,
    const int* __restrict__ ei, const u16* __restrict__ WcT,
    const float* __restrict__ cbv,
    const float* __restrict__ lag, const float* __restrict__ lab,
    const u16* __restrict__ WmT, const float* __restrict__ bm_l,
    const float* __restrict__ lmg, const float* __restrict__ lmb,
    float* __restrict__ agg, int E) {
  __shared__ __align__(16) u16 C1[16 * 1032];
  __shared__ __align__(16) u16 A2p[12 * 512];   // aliased as C2 float[16][132]
  __shared__ int did16[16];
  float* C2 = (float*)A2p;
  const int tid = threadIdx.x;
  const int e0 = blockIdx.x * 16;
  const int w = tid >> 6, l = tid & 63;
  const int lq = l >> 4, ln = l & 15;
  const float scale = 0.051031036307982884f;  // 1/sqrt(384)

  if (tid < 16) did16[tid] = ei[E + e0 + tid];

  const int r = tid >> 4, lx = tid & 15;
  const int hA = r >> 3, eA = r & 7;

  // ---- Prefetch gathers for both sub-batches ----
  bf16x8 qv[2], kdv[2], ksv[2], pdv[2][3], psv[2][3];
#pragma unroll
  for (int s = 0; s < 2; ++s) {
    int edge = e0 + s * 8 + eA;
    int dstn = ei[E + edge], srcn = ei[edge];
    const u16* db = qkp + (size_t)dstn * 2048;
    const u16* sb = qkp + (size_t)srcn * 2048;
    qv[s]  = *(const bf16x8*)&db[hA * 128 + lx * 8];
    kdv[s] = *(const bf16x8*)&db[256 + hA * 128 + lx * 8];
    ksv[s] = *(const bf16x8*)&sb[256 + hA * 128 + lx * 8];
#pragma unroll
    for (int p = 0; p < 3; ++p) {
      pdv[s][p] = *(const bf16x8*)&db[512 + hA * 384 + p * 128 + lx * 8];
      psv[s][p] = *(const bf16x8*)&sb[512 + 768 + hA * 384 + p * 128 + lx * 8];
    }
  }

  // ---- GEMM1: C1[16][1024] = efb @ WcT ----
  {
    bf16x8 afr[4];
    const u16* ab = efb + (size_t)(e0 + ln) * 128 + lq * 8;
#pragma unroll
    for (int ks = 0; ks < 4; ++ks) afr[ks] = *(const bf16x8*)(ab + ks * 32);
    for (int nt = 0; nt < 16; ++nt) {
      int g = w * 16 + nt;
      const u16* bb = WcT + (size_t)(g * 16 + ln) * 128 + lq * 8;
      f32x4 acc = {0.f, 0.f, 0.f, 0.f};
#pragma unroll
      for (int ks = 0; ks < 4; ++ks)
        acc = __builtin_amdgcn_mfma_f32_16x16x32_bf16(
            afr[ks], *(const bf16x8*)(bb + ks * 32), acc, 0, 0, 0);
      int col = g * 16 + ln;
#pragma unroll
      for (int rr = 0; rr < 4; ++rr) C1[(lq * 4 + rr) * 1032 + col] = f2bf(acc[rr]);
    }
  }
  __syncthreads();

  for (int s = 0; s < 2; ++s) {
    // ---- Phase A+4 fused: alpha -> LN384 -> gate (regs) -> t -> A2p ----
    {
      bf16x8 sea = *(const bf16x8*)&C1[(s * 8 + eA) * 1032 + hA * 128 + lx * 8];
      float a0[8], a1[8], a2[8];
      float sacc = 0.f, s2acc = 0.f;
#pragma unroll
      for (int j = 0; j < 8; ++j) {
        float qf = bf2f((u16)qv[s][j]);
        float x0 = qf * bf2f((u16)kdv[s][j]) * scale;
        float x1 = qf * bf2f((u16)ksv[s][j]) * scale;
        float x2 = qf * bf2f((u16)sea[j]) * scale;
        a0[j] = x0; a1[j] = x1; a2[j] = x2;
        sacc += x0 + x1 + x2;
        s2acc += x0 * x0 + x1 * x1 + x2 * x2;
      }
#pragma unroll
      for (int mm = 1; mm < 16; mm <<= 1) {
        sacc += __shfl_xor(sacc, mm); s2acc += __shfl_xor(s2acc, mm);
      }
      float mean = sacc * (1.f / C3DIM);
      float rstd = rsqrtf(s2acc * (1.f / C3DIM) - mean * mean + 1e-5f);
#pragma unroll
      for (int p = 0; p < 3; ++p) {
        const float* lg = lag + p * 128 + lx * 8;
        const float* lb = lab + p * 128 + lx * 8;
        f32x4 g0 = *(const f32x4*)lg, g1 = *(const f32x4*)(lg + 4);
        f32x4 b0 = *(const f32x4*)lb, b1 = *(const f32x4*)(lb + 4);
        f32x4 c0 = *(const f32x4*)&cbv[hA * 384 + p * 128 + lx * 8];
        f32x4 c1 = *(const f32x4*)&cbv[hA * 384 + p * 128 + lx * 8 + 4];
        bf16x8 pe = *(const bf16x8*)&C1[(s * 8 + eA) * 1032 + 256 + hA * 384 + p * 128 + lx * 8];
        bf16x8 outv;
#pragma unroll
        for (int j = 0; j < 8; ++j) {
          float av = p == 0 ? a0[j] : (p == 1 ? a1[j] : a2[j]);
          float gg = j < 4 ? g0[j] : g1[j - 4];
          float bb2 = j < 4 ? b0[j] : b1[j - 4];
          float cbj = j < 4 ? c0[j] : c1[j - 4];
          float z = (av - mean) * rstd * gg + bb2;
          float gate = 1.f / (1.f + expf(-z));
          float t = (bf2f((u16)pe[j]) + bf2f((u16)pdv[s][p][j]) +
                     bf2f((u16)psv[s][p][j]) + cbj) * gate;
          outv[j] = (short)f2bf(t);
        }
        int ks = p * 4 + (lx >> 2), qq = lx & 3;
        int slot = (((r ^ (qq << 2)) + ks) & 15) | (qq << 4);
        *(bf16x8*)&A2p[ks * 512 + slot * 8] = outv;
      }
    }
    __syncthreads();

    // ---- GEMM2 ----
    {
      bf16x8 af2[12];
#pragma unroll
      for (int ks = 0; ks < 12; ++ks) {
        int slot = (((ln ^ (lq << 2)) + ks) & 15) | (lq << 4);
        af2[ks] = *(const bf16x8*)&A2p[ks * 512 + slot * 8];
      }
      __syncthreads();  // all reads of A2p complete before aliased C2 writes
#pragma unroll
      for (int nt = 0; nt < 2; ++nt) {
        int g = w * 2 + nt;
        const u16* bb = WmT + (size_t)(g * 16 + ln) * 384 + lq * 8;
        f32x4 acc = {0.f, 0.f, 0.f, 0.f};
#pragma unroll
        for (int ks = 0; ks < 12; ++ks)
          acc = __builtin_amdgcn_mfma_f32_16x16x32_bf16(
              af2[ks], *(const bf16x8*)(bb + ks * 32), acc, 0, 0, 0);
        int col = g * 16 + ln;
        float bcol = bm_l[col];
#pragma unroll
        for (int rr = 0; rr < 4; ++rr) C2[(lq * 4 + rr) * 132 + col] = acc[rr] + bcol;
      }
    }
    __syncthreads();

    // ---- LN128 + scatter (unsorted dst -> uncontended atomics) ----
    {
      for (int rw = w; rw < 16; rw += 4) {
        float v0 = C2[rw * 132 + l], v1 = C2[rw * 132 + l + 64];
        float sa = v0 + v1, s2a = v0 * v0 + v1 * v1;
#pragma unroll
        for (int off2 = 32; off2 > 0; off2 >>= 1) {
          sa += __shfl_down(sa, off2); s2a += __shfl_down(s2a, off2);
        }
        sa = __shfl(sa, 0); s2a = __shfl(s2a, 0);
        float mean = sa * (1.f / CDIM);
        float rstd = rsqrtf(s2a * (1.f / CDIM) - mean * mean + 1e-5f);
        int h = rw >> 3, e = rw & 7;
        int dstn = did16[s * 8 + e];
        float o0 = (v0 - mean) * rstd * lmg[l] + lmb[l];
        float o1 = (v1 - mean) * rstd * lmg[l + 64] + lmb[l + 64];
        atomicAdd(&agg[(size_t)dstn * HCDIM + h * CDIM + l], o0);
        atomicAdd(&agg[(size_t)dstn * HCDIM + h * CDIM + l + 64], o1);
      }
    }
    __syncthreads();
  }
}

// ---------------- fused BN(from sums) + SiLU + skip --------------------------
__global__ void bn_silu_skip_kernel(
    const float* __restrict__ o, const float* __restrict__ skip,
    const float* __restrict__ cs, const float* __restrict__ cs2,
    const float* __restrict__ g, const float* __restrict__ b,
    float* __restrict__ nf, u16* __restrict__ nfb) {
  int idx = blockIdx.x * blockDim.x + threadIdx.x;
  if (idx >= N_NODES * CDIM) return;
  int c = idx & (CDIM - 1);
  float m = cs[c] * (1.f / N_NODES);
  float var = cs2[c] * (1.f / N_NODES) - m * m;
  float rstd = rsqrtf(var + 1e-5f);
  float x = (o[idx] - m) * rstd * g[c] + b[c];
  float sig = 1.f / (1.f + expf(-x));
  float val = x * sig + skip[idx];
  nf[idx] = val;
  nfb[idx] = f2bf(val);
}

// ---------------- fused mean-pool + feats (batch is sorted) ------------------
__global__ __launch_bounds__(256) void poolfeats_kernel(
    const float* __restrict__ nf, const int* __restrict__ batch,
    const float* __restrict__ pge, const float* __restrict__ cse,
    float* __restrict__ feats) {
  const int b = blockIdx.x, tid = threadIdx.x;
  // binary search [lo,hi) of graph b in sorted batch
  int lo = 0, hi = N_NODES;
  {
    int L = 0, R = N_NODES;
    while (L < R) { int m2 = (L + R) >> 1; if (batch[m2] < b) L = m2 + 1; else R = m2; }
    lo = L;
    L = lo; R = N_NODES;
    while (L < R) { int m2 = (L + R) >> 1; if (batch[m2] <= b) L = m2 + 1; else R = m2; }
    hi = L;
  }
  __shared__ float sacc[2][128];
  const int half = tid >> 7, c = tid & 127;
  float s = 0.f;
  for (int n = lo + half; n < hi; n += 2) s += nf[(size_t)n * CDIM + c];
  sacc[half][c] = s;
  __syncthreads();
  float cntf = fmaxf((float)(hi - lo), 1.f);
  if (tid < 128) feats[b * 167 + tid] = (sacc[0][tid] + sacc[1][tid]) / cntf;
  else if (tid < 160) feats[b * 167 + 128 + (tid - 128)] = pge[b * 32 + (tid - 128)];
  else if (tid < 167) feats[b * 167 + 160 + (tid - 160)] = cse[b * 7 + (tid - 160)];
}

// ---------------- fused fc + out ---------------------------------------------
__global__ __launch_bounds__(256) void fcout_kernel(
    const float* __restrict__ feats, const float* __restrict__ fc_W,
    const float* __restrict__ fc_b, const float* __restrict__ ow,
    const float* __restrict__ ob, float* __restrict__ out) {
  const int b = blockIdx.x, tid = threadIdx.x;
  __shared__ float sf[167];
  if (tid < 167) sf[tid] = feats[b * 167 + tid];
  __syncthreads();
  float acc0 = fc_b[tid], acc1 = fc_b[tid + 256];
  for (int k = 0; k < 167; ++k) {
    float fv = sf[k];
    acc0 += fv * fc_W[(size_t)k * 512 + tid];
    acc1 += fv * fc_W[(size_t)k * 512 + tid + 256];
  }
  float h0 = acc0 / (1.f + expf(-acc0));
  float h1 = acc1 / (1.f + expf(-acc1));
  float s = h0 * ow[tid] + h1 * ow[tid + 256];
  __shared__ float red[4];
#pragma unroll
  for (int off = 32; off > 0; off >>= 1) s += __shfl_down(s, off);
  if ((tid & 63) == 0) red[tid >> 6] = s;
  __syncthreads();
  if (tid == 0) out[b] = red[0] + red[1] + red[2] + red[3] + ob[0];
}

// ---------------- launch -----------------------------------------------------
extern "C" void kernel_launch(void* const* d_in, const int* in_sizes, int n_in,
                              void* d_out, int out_size, void* d_ws, size_t ws_size,
                              hipStream_t stream) {
  const float* x         = (const float*)d_in[0];
  const float* edge_attr = (const float*)d_in[1];
  const float* pge       = (const float*)d_in[2];
  const float* cse       = (const float*)d_in[3];
  const int*   ei        = (const int*)d_in[4];
  const int*   batch     = (const int*)d_in[5];
  const float* atom_W    = (const float*)d_in[6];
  const float* atom_b    = (const float*)d_in[7];
  const float* edge_W    = (const float*)d_in[8];
  const float* edge_b    = (const float*)d_in[9];
  const float* Wq        = (const float*)d_in[10];
  const float* bq        = (const float*)d_in[11];
  const float* Wk        = (const float*)d_in[12];
  const float* bk        = (const float*)d_in[13];
  const float* Wv        = (const float*)d_in[14];
  const float* bv        = (const float*)d_in[15];
  const float* We        = (const float*)d_in[16];
  const float* Wmu       = (const float*)d_in[17];
  const float* bmu       = (const float*)d_in[18];
  const float* Wm        = (const float*)d_in[19];
  const float* bm        = (const float*)d_in[20];
  const float* ln_m_g    = (const float*)d_in[21];
  const float* ln_m_b    = (const float*)d_in[22];
  const float* ln_a_g    = (const float*)d_in[23];
  const float* ln_a_b    = (const float*)d_in[24];
  const float* Wc        = (const float*)d_in[25];
  const float* bc        = (const float*)d_in[26];
  const float* bn_g      = (const float*)d_in[27];
  const float* bn_b      = (const float*)d_in[28];
  const float* Wskip     = (const float*)d_in[29];
  const float* bskip     = (const float*)d_in[30];
  const float* fc_W      = (const float*)d_in[31];
  const float* fc_b      = (const float*)d_in[32];
  const float* out_W     = (const float*)d_in[33];
  const float* out_b     = (const float*)d_in[34];

  float* ws = (float*)d_ws;
  size_t off = 0;
  float* nf    = ws + off; off += (size_t)N_NODES * CDIM;
  float* agg   = ws + off; off += (size_t)N_NODES * HCDIM;
  float* o     = ws + off; off += (size_t)N_NODES * CDIM;
  float* skip  = ws + off; off += (size_t)N_NODES * CDIM;
  float* cbv   = ws + off; off += 768;
  float* ball  = ws + off; off += 2048;
  float* csum  = ws + off; off += CDIM;
  float* csum2 = ws + off; off += CDIM;
  float* feats = ws + off; off += (size_t)N_GRAPH * 167;
  u16* efb   = (u16*)(ws + off); off += (size_t)N_EDGES * 64;     // E*128 u16
  u16* WcT   = (u16*)(ws + off); off += 65536;                    // 1024*128 u16
  u16* WmTb  = (u16*)(ws + off); off += 24576;                    // 128*384 u16
  u16* nfb   = (u16*)(ws + off); off += (size_t)N_NODES * 64;     // N*128 u16
  u16* aggb  = (u16*)(ws + off); off += (size_t)N_NODES * 128;    // N*256 u16
  u16* qkp   = (u16*)(ws + off); off += (size_t)N_NODES * 1024;   // N*2048 u16
  u16* WallT = (u16*)(ws + off); off += 131072;                   // 2048*128 u16
  u16* WcTw  = (u16*)(ws + off); off += 16384;                    // 128*256 u16
  u16* WskT  = (u16*)(ws + off); off += 8192;                     // 128*128 u16
  u16* xpad  = (u16*)(ws + off); off += (size_t)N_NODES * 48;     // N*96 u16
  u16* epad  = (u16*)(ws + off); off += (size_t)N_EDGES * 32;     // E*64 u16
  u16* atomWT= (u16*)(ws + off); off += 6144;                     // 128*96 u16
  u16* WeT2  = (u16*)(ws + off); off += 4096;                     // 128*64 u16

  // ---- one-time: pack inputs, initial MFMA GEMMs ----
  pack_init_kernel<<<dim3(256, 4), 256, 0, stream>>>(x, edge_attr, atom_W, edge_W,
                                                     xpad, epad, atomWT, WeT2);
  mfma_gemm_kernel<0, 0><<<dim3(2, 79), 256, 0, stream>>>(
      xpad, atomWT, atom_b, nf, nfb, nullptr, nullptr, N_NODES, 96, CDIM);
  mfma_gemm_kernel<1, 0><<<dim3(2, 782), 256, 0, stream>>>(
      epad, WeT2, edge_b, efb, nullptr, nullptr, nullptr, N_EDGES, 64, CDIM);

  for (int i = 0; i < 2; ++i) {
    const float* Wv_i  = Wv + (size_t)i * CDIM * HCDIM;
    const float* We_i  = We + (size_t)i * CDIM * HCDIM;
    const float* Wmu_i = Wmu + (size_t)i * C3DIM * C3DIM;
    compose_kernel<<<dim3(6, 2, 6), 256, 0, stream>>>(Wv_i, We_i, Wmu_i, WallT, WcT);
    pack_all_kernel<<<dim3(192, 9), 256, 0, stream>>>(
        Wq + (size_t)i * CDIM * HCDIM, Wk + (size_t)i * CDIM * HCDIM,
        Wc + (size_t)i * HCDIM * CDIM, Wskip + (size_t)i * CDIM * CDIM,
        Wm + (size_t)i * C3DIM * CDIM, bmu + i * C3DIM, bv + i * HCDIM, Wmu_i,
        bq + i * HCDIM, bk + i * HCDIM, We_i,
        WallT, WcTw, WskT, WmTb, cbv, ball, agg, csum, csum2, WcT);

    // qkp = nfb @ [Wq|Wk|WP12]  (N=2048, bf16 out)
    mfma_gemm_kernel<1, 0><<<dim3(32, 79), 256, 0, stream>>>(
        nfb, WallT, ball, qkp, nullptr, nullptr, nullptr, N_NODES, CDIM, 2048);

    edge_kernel<<<dim3(N_EDGES / 16), dim3(256), 0, stream>>>(
        qkp, efb, ei, WcT, cbv,
        ln_a_g + i * C3DIM, ln_a_b + i * C3DIM,
        WmTb, bm + i * CDIM,
        ln_m_g + i * CDIM, ln_m_b + i * CDIM, agg, N_EDGES);

    pack_bf16_kernel<<<dim3((N_NODES * 256 + 255) / 256), dim3(256), 0, stream>>>(
        agg, aggb, N_NODES * 256);
    mfma_gemm_kernel<0, 1><<<dim3(2, 79), 256, 0, stream>>>(
        aggb, WcTw, bc + i * CDIM, o, nullptr, csum, csum2, N_NODES, HCDIM, CDIM);
    mfma_gemm_kernel<0, 0><<<dim3(2, 79), 256, 0, stream>>>(
        nfb, WskT, bskip + i * CDIM, skip, nullptr, nullptr, nullptr, N_NODES, CDIM, CDIM);
    bn_silu_skip_kernel<<<dim3((N_NODES * CDIM + 255) / 256), dim3(256), 0, stream>>>(
        o, skip, csum, csum2, bn_g + i * CDIM, bn_b + i * CDIM, nf, nfb);
  }

  poolfeats_kernel<<<dim3(N_GRAPH), 256, 0, stream>>>(nf, batch, pge, cse, feats);
  fcout_kernel<<<dim3(N_GRAPH), 256, 0, stream>>>(feats, fc_W, fc_b, out_W, out_b,
                                                  (float*)d_out);
}

// Round 10
// 1217.579 us; speedup vs baseline: 1.5782x; 1.0223x over previous
//
#include <hip/hip_runtime.h>
#include <math.h>

#define N_NODES 10000
#define N_EDGES 100000
#define N_GRAPH 64
#define CDIM 128
#define HCDIM 256
#define C3DIM 384
#define QKPW 2176   // qkp row width: [q(256)|k(256)|P12(1536)|skip(128)]

typedef unsigned short u16;
typedef __attribute__((ext_vector_type(8))) short bf16x8;
typedef __attribute__((ext_vector_type(4))) float f32x4;

__device__ __forceinline__ u16 f2bf(float f) {
  union { float f; unsigned int u; } x; x.f = f;
  unsigned int u = x.u + 0x7fffu + ((x.u >> 16) & 1u);
  return (u16)(u >> 16);
}
__device__ __forceinline__ float bf2f(u16 h) {
  union { unsigned int u; float f; } x; x.u = ((unsigned int)h) << 16;
  return x.f;
}

// ---------------- MFMA dense GEMM ------------------------------------------
// A_F32: A operand is fp32, converted to bf16 in-register (fuses pack step).
template<int OUT_BF16, int DO_STATS, int A_F32>
__global__ __launch_bounds__(256) void mfma_gemm_kernel(
    const void* __restrict__ Ain, const u16* __restrict__ WT,
    const float* __restrict__ bias, void* __restrict__ Y,
    u16* __restrict__ Ymirror, float* __restrict__ cs, float* __restrict__ cs2,
    int M, int K, int N) {
  const int tid = threadIdx.x;
  const int w = tid >> 6, l = tid & 63;
  const int lq = l >> 4, ln = l & 15;
  const int bm = blockIdx.y * 128, bn = blockIdx.x * 64;
  int ra = bm + w * 32 + ln;      if (ra > M - 1) ra = M - 1;
  int rb = bm + w * 32 + 16 + ln; if (rb > M - 1) rb = M - 1;
  f32x4 acc[2][4];
#pragma unroll
  for (int g = 0; g < 2; ++g)
#pragma unroll
    for (int nt = 0; nt < 4; ++nt) acc[g][nt] = {0.f, 0.f, 0.f, 0.f};
  for (int k0 = 0; k0 < K; k0 += 32) {
    bf16x8 a0, a1;
    if (A_F32) {
      const float* Af = (const float*)Ain;
      f32x4 p0 = *(const f32x4*)&Af[(size_t)ra * K + k0 + lq * 8];
      f32x4 p1 = *(const f32x4*)&Af[(size_t)ra * K + k0 + lq * 8 + 4];
      f32x4 p2 = *(const f32x4*)&Af[(size_t)rb * K + k0 + lq * 8];
      f32x4 p3 = *(const f32x4*)&Af[(size_t)rb * K + k0 + lq * 8 + 4];
#pragma unroll
      for (int j = 0; j < 4; ++j) {
        a0[j] = (short)f2bf(p0[j]); a0[4 + j] = (short)f2bf(p1[j]);
        a1[j] = (short)f2bf(p2[j]); a1[4 + j] = (short)f2bf(p3[j]);
      }
    } else {
      const u16* Ab = (const u16*)Ain;
      a0 = *(const bf16x8*)&Ab[(size_t)ra * K + k0 + lq * 8];
      a1 = *(const bf16x8*)&Ab[(size_t)rb * K + k0 + lq * 8];
    }
#pragma unroll
    for (int nt = 0; nt < 4; ++nt) {
      bf16x8 b = *(const bf16x8*)&WT[(size_t)(bn + nt * 16 + ln) * K + k0 + lq * 8];
      acc[0][nt] = __builtin_amdgcn_mfma_f32_16x16x32_bf16(a0, b, acc[0][nt], 0, 0, 0);
      acc[1][nt] = __builtin_amdgcn_mfma_f32_16x16x32_bf16(a1, b, acc[1][nt], 0, 0, 0);
    }
  }
#pragma unroll
  for (int g = 0; g < 2; ++g) {
    int rowbase = bm + w * 32 + g * 16 + lq * 4;
#pragma unroll
    for (int nt = 0; nt < 4; ++nt) {
      int gn = bn + nt * 16 + ln;
      float bv = bias ? bias[gn] : 0.f;
#pragma unroll
      for (int r = 0; r < 4; ++r) {
        int gm = rowbase + r;
        if (gm < M) {
          float val = acc[g][nt][r] + bv;
          if (OUT_BF16) ((u16*)Y)[(size_t)gm * N + gn] = f2bf(val);
          else          ((float*)Y)[(size_t)gm * N + gn] = val;
          if (Ymirror)  Ymirror[(size_t)gm * N + gn] = f2bf(val);
        }
      }
    }
  }
  if (DO_STATS) {
#pragma unroll
    for (int nt = 0; nt < 4; ++nt) {
      int gn = bn + nt * 16 + ln;
      float bv = bias ? bias[gn] : 0.f;
      float s = 0.f, s2 = 0.f;
#pragma unroll
      for (int g = 0; g < 2; ++g) {
        int rowbase = bm + w * 32 + g * 16 + lq * 4;
#pragma unroll
        for (int r = 0; r < 4; ++r) {
          if (rowbase + r < M) {
            float v = acc[g][nt][r] + bv;
            s += v; s2 += v * v;
          }
        }
      }
      s += __shfl_xor(s, 16); s2 += __shfl_xor(s2, 16);
      s += __shfl_xor(s, 32); s2 += __shfl_xor(s2, 32);
      if (lq == 0) { atomicAdd(&cs[gn], s); atomicAdd(&cs2[gn], s2); }
    }
  }
}

// ---------------- init packs: xpad/epad/atomWT/WeT2 (z-sliced) ---------------
__global__ void pack_init_kernel(
    const float* __restrict__ x, const float* __restrict__ ea,
    const float* __restrict__ atom_W, const float* __restrict__ edge_W,
    u16* __restrict__ xpad, u16* __restrict__ epad,
    u16* __restrict__ atomWT, u16* __restrict__ WeT2) {
  int z = blockIdx.y;
  int idx0 = blockIdx.x * 256 + threadIdx.x;
  const int stride = 256 * 256;
  if (z == 0) {
    for (int idx = idx0; idx < N_NODES * 96; idx += stride) {
      int n = idx / 96, k = idx - n * 96;
      xpad[idx] = (k < 92) ? f2bf(x[(size_t)n * 92 + k]) : (u16)0;
    }
  } else if (z == 1) {
    for (int idx = idx0; idx < N_EDGES * 64; idx += stride) {
      int e = idx >> 6, k = idx & 63;
      epad[idx] = (k < 50) ? f2bf(ea[(size_t)e * 50 + k]) : (u16)0;
    }
  } else if (z == 2) {
    if (idx0 < 128 * 96) { int n = idx0 / 96, k = idx0 - n * 96;
      atomWT[idx0] = (k < 92) ? f2bf(atom_W[(size_t)k * 128 + n]) : (u16)0; }
  } else {
    if (idx0 < 128 * 64) { int n = idx0 >> 6, k = idx0 & 63;
      WeT2[idx0] = (k < 50) ? f2bf(edge_W[(size_t)k * 128 + n]) : (u16)0; }
  }
}

// ---------------- merged prep kernel ----------------------------------------
// blocks 0..71: compose GEMM (Wmu folds) -> bf16 WallT[512:2048] / WcT[256:1024]
// blocks 72..1799: pack slices (z = (b-72)/192):
//  z0: Wq->WallT[0:256]  z1: Wk->WallT[256:512]  z2: WcTw  z3: Wskip->WallT[2048:2176]
//  z4: WmTb  z5: cbv  z6: ball  z7: zero agg+csum  z8: We->WcT[0:256]
__global__ __launch_bounds__(256) void prep_kernel(
    const float* __restrict__ Wv, const float* __restrict__ We_l,
    const float* __restrict__ Wmu,
    const float* __restrict__ Wq, const float* __restrict__ Wk,
    const float* __restrict__ Wc, const float* __restrict__ Wsk,
    const float* __restrict__ Wm_l, const float* __restrict__ bmu,
    const float* __restrict__ bv_l,
    const float* __restrict__ bq_l, const float* __restrict__ bk_l,
    const float* __restrict__ bsk_l,
    u16* __restrict__ WallT, u16* __restrict__ WcT, u16* __restrict__ WcTw,
    u16* __restrict__ WmTb, float* __restrict__ cbv, float* __restrict__ ball,
    float* __restrict__ agg, float* __restrict__ cs, float* __restrict__ cs2) {
  __shared__ float As[16][68];
  __shared__ float Bs[16][65];
  const int b = blockIdx.x;
  const int tid = threadIdx.x;
  if (b < 72) {
    // ---- compose path ----
    const int zc = b / 12, rem = b % 12;
    const int by = rem / 6, bx = rem % 6;
    const float* Ap; const float* Bp; u16* Cp; int colbase;
    if (zc < 4) {
      int part = zc >> 1, h = zc & 1;
      Ap = Wv + h * 128; Bp = Wmu + part * 128 * 384;
      Cp = WallT; colbase = 512 + part * 768 + h * 384;
    } else {
      int h = zc - 4;
      Ap = We_l + h * 128; Bp = Wmu + 256 * 384;
      Cp = WcT; colbase = 256 + h * 384;
    }
    const int bm = by * 64, bn = bx * 64;
    const int tx = tid & 15, ty = tid >> 4;
    float acc[4][4] = {};
    for (int k0 = 0; k0 < 128; k0 += 16) {
#pragma unroll
      for (int i = 0; i < 4; ++i) {
        int l = tid + i * 256;
        int kk = l & 15, m = l >> 4;
        As[kk][m] = Ap[(size_t)(bm + m) * 256 + k0 + kk];
      }
#pragma unroll
      for (int i = 0; i < 4; ++i) {
        int l = tid + i * 256;
        int n = l & 63, kk = l >> 6;
        Bs[kk][n] = Bp[(size_t)(k0 + kk) * 384 + bn + n];
      }
      __syncthreads();
#pragma unroll
      for (int kk = 0; kk < 16; ++kk) {
        float a[4], bb[4];
#pragma unroll
        for (int i = 0; i < 4; ++i) a[i] = As[kk][ty * 4 + i];
#pragma unroll
        for (int j = 0; j < 4; ++j) bb[j] = Bs[kk][tx * 4 + j];
#pragma unroll
        for (int i = 0; i < 4; ++i)
#pragma unroll
          for (int j = 0; j < 4; ++j) acc[i][j] += a[i] * bb[j];
      }
      __syncthreads();
    }
#pragma unroll
    for (int i = 0; i < 4; ++i) {
      int gk = bm + ty * 4 + i;
#pragma unroll
      for (int j = 0; j < 4; ++j) {
        int gcol = colbase + bn + tx * 4 + j;
        Cp[(size_t)gcol * 128 + gk] = f2bf(acc[i][j]);
      }
    }
    return;
  }
  // ---- pack path ----
  const int pb = b - 72;
  const int z = pb / 192;
  const int idx = (pb % 192) * 256 + tid;
  if (z == 0) {
    if (idx < 32768) { int col = idx >> 7, kk = idx & 127;
      WallT[(size_t)col * 128 + kk] = f2bf(Wq[(size_t)kk * 256 + col]); }
  } else if (z == 1) {
    if (idx < 32768) { int col = idx >> 7, kk = idx & 127;
      WallT[(size_t)(256 + col) * 128 + kk] = f2bf(Wk[(size_t)kk * 256 + col]); }
  } else if (z == 2) {
    if (idx < 32768) { int col = idx >> 8, kk = idx & 255;
      WcTw[(size_t)col * 256 + kk] = f2bf(Wc[(size_t)kk * 128 + col]); }
  } else if (z == 3) {
    if (idx < 16384) { int col = idx >> 7, kk = idx & 127;
      WallT[(size_t)(2048 + col) * 128 + kk] = f2bf(Wsk[(size_t)kk * 128 + col]); }
  } else if (z == 4) {
    if (idx < 49152) { int col = idx / 384, kk = idx - col * 384;
      WmTb[idx] = f2bf(Wm_l[(size_t)kk * 128 + col]); }
  } else if (z == 5) {
    if (idx < 768) {
      int h2 = idx / 384, g = idx - h2 * 384;
      float s = bmu[g];
      for (int d = 0; d < 128; ++d)
        s += bv_l[h2 * 128 + d] * (Wmu[(size_t)d * 384 + g] + Wmu[(size_t)(128 + d) * 384 + g]);
      cbv[idx] = s;
    }
  } else if (z == 6) {
    if (idx < QKPW) {
      float v = 0.f;
      if (idx < 256) v = bq_l[idx];
      else if (idx < 512) v = bk_l[idx - 256];
      else if (idx >= 2048) v = bsk_l[idx - 2048];
      ball[idx] = v;
    }
  } else if (z == 7) {
    for (int p = idx; p < N_NODES * HCDIM; p += 192 * 256) agg[p] = 0.f;
    if (idx < 128) { cs[idx] = 0.f; cs2[idx] = 0.f; }
  } else {
    if (idx < 32768) { int col = idx >> 7, kk = idx & 127;
      WcT[(size_t)col * 128 + kk] = f2bf(We_l[(size_t)kk * 256 + col]); }
  }
}

// ---------------- fused per-edge kernel (MFMA, 16 edges/block) ---------------
// qkp row per node (QKPW=2176): [q(256) | k(256) | P12(1536) | skip(128)]
__global__ __launch_bounds__(256, 3) void edge_kernel(
    const u16* __restrict__ qkp, const u16* __restrict__ efb,
    const int* __restrict__ ei, const u16* __restrict__ WcT,
    const float* __restrict__ cbv,
    const float* __restrict__ lag, const float* __restrict__ lab,
    const u16* __restrict__ WmT, const float* __restrict__ bm_l,
    const float* __restrict__ lmg, const float* __restrict__ lmb,
    float* __restrict__ agg, int E) {
  __shared__ __align__(16) u16 C1[16 * 1032];
  __shared__ __align__(16) u16 A2p[12 * 512];   // aliased as C2 float[16][132]
  __shared__ int did16[16];
  float* C2 = (float*)A2p;
  const int tid = threadIdx.x;
  const int e0 = blockIdx.x * 16;
  const int w = tid >> 6, l = tid & 63;
  const int lq = l >> 4, ln = l & 15;
  const float scale = 0.051031036307982884f;  // 1/sqrt(384)

  if (tid < 16) did16[tid] = ei[E + e0 + tid];

  const int r = tid >> 4, lx = tid & 15;
  const int hA = r >> 3, eA = r & 7;

  // ---- Prefetch gathers for both sub-batches ----
  bf16x8 qv[2], kdv[2], ksv[2], pdv[2][3], psv[2][3];
#pragma unroll
  for (int s = 0; s < 2; ++s) {
    int edge = e0 + s * 8 + eA;
    int dstn = ei[E + edge], srcn = ei[edge];
    const u16* db = qkp + (size_t)dstn * QKPW;
    const u16* sb = qkp + (size_t)srcn * QKPW;
    qv[s]  = *(const bf16x8*)&db[hA * 128 + lx * 8];
    kdv[s] = *(const bf16x8*)&db[256 + hA * 128 + lx * 8];
    ksv[s] = *(const bf16x8*)&sb[256 + hA * 128 + lx * 8];
#pragma unroll
    for (int p = 0; p < 3; ++p) {
      pdv[s][p] = *(const bf16x8*)&db[512 + hA * 384 + p * 128 + lx * 8];
      psv[s][p] = *(const bf16x8*)&sb[512 + 768 + hA * 384 + p * 128 + lx * 8];
    }
  }

  // ---- GEMM1: C1[16][1024] = efb @ WcT ----
  {
    bf16x8 afr[4];
    const u16* ab = efb + (size_t)(e0 + ln) * 128 + lq * 8;
#pragma unroll
    for (int ks = 0; ks < 4; ++ks) afr[ks] = *(const bf16x8*)(ab + ks * 32);
    for (int nt = 0; nt < 16; ++nt) {
      int g = w * 16 + nt;
      const u16* bb = WcT + (size_t)(g * 16 + ln) * 128 + lq * 8;
      f32x4 acc = {0.f, 0.f, 0.f, 0.f};
#pragma unroll
      for (int ks = 0; ks < 4; ++ks)
        acc = __builtin_amdgcn_mfma_f32_16x16x32_bf16(
            afr[ks], *(const bf16x8*)(bb + ks * 32), acc, 0, 0, 0);
      int col = g * 16 + ln;
#pragma unroll
      for (int rr = 0; rr < 4; ++rr) C1[(lq * 4 + rr) * 1032 + col] = f2bf(acc[rr]);
    }
  }
  __syncthreads();

  for (int s = 0; s < 2; ++s) {
    // ---- Phase A+4 fused: alpha -> LN384 -> gate (regs) -> t -> A2p ----
    {
      bf16x8 sea = *(const bf16x8*)&C1[(s * 8 + eA) * 1032 + hA * 128 + lx * 8];
      float a0[8], a1[8], a2[8];
      float sacc = 0.f, s2acc = 0.f;
#pragma unroll
      for (int j = 0; j < 8; ++j) {
        float qf = bf2f((u16)qv[s][j]);
        float x0 = qf * bf2f((u16)kdv[s][j]) * scale;
        float x1 = qf * bf2f((u16)ksv[s][j]) * scale;
        float x2 = qf * bf2f((u16)sea[j]) * scale;
        a0[j] = x0; a1[j] = x1; a2[j] = x2;
        sacc += x0 + x1 + x2;
        s2acc += x0 * x0 + x1 * x1 + x2 * x2;
      }
#pragma unroll
      for (int mm = 1; mm < 16; mm <<= 1) {
        sacc += __shfl_xor(sacc, mm); s2acc += __shfl_xor(s2acc, mm);
      }
      float mean = sacc * (1.f / C3DIM);
      float rstd = rsqrtf(s2acc * (1.f / C3DIM) - mean * mean + 1e-5f);
#pragma unroll
      for (int p = 0; p < 3; ++p) {
        const float* lg = lag + p * 128 + lx * 8;
        const float* lb = lab + p * 128 + lx * 8;
        f32x4 g0 = *(const f32x4*)lg, g1 = *(const f32x4*)(lg + 4);
        f32x4 b0 = *(const f32x4*)lb, b1 = *(const f32x4*)(lb + 4);
        f32x4 c0 = *(const f32x4*)&cbv[hA * 384 + p * 128 + lx * 8];
        f32x4 c1 = *(const f32x4*)&cbv[hA * 384 + p * 128 + lx * 8 + 4];
        bf16x8 pe = *(const bf16x8*)&C1[(s * 8 + eA) * 1032 + 256 + hA * 384 + p * 128 + lx * 8];
        bf16x8 outv;
#pragma unroll
        for (int j = 0; j < 8; ++j) {
          float av = p == 0 ? a0[j] : (p == 1 ? a1[j] : a2[j]);
          float gg = j < 4 ? g0[j] : g1[j - 4];
          float bb2 = j < 4 ? b0[j] : b1[j - 4];
          float cbj = j < 4 ? c0[j] : c1[j - 4];
          float z = (av - mean) * rstd * gg + bb2;
          float gate = 1.f / (1.f + expf(-z));
          float t = (bf2f((u16)pe[j]) + bf2f((u16)pdv[s][p][j]) +
                     bf2f((u16)psv[s][p][j]) + cbj) * gate;
          outv[j] = (short)f2bf(t);
        }
        int ks = p * 4 + (lx >> 2), qq = lx & 3;
        int slot = (((r ^ (qq << 2)) + ks) & 15) | (qq << 4);
        *(bf16x8*)&A2p[ks * 512 + slot * 8] = outv;
      }
    }
    __syncthreads();

    // ---- GEMM2: m[16][128] = A2 @ WmT ----
    {
      bf16x8 af2[12];
#pragma unroll
      for (int ks = 0; ks < 12; ++ks) {
        int slot = (((ln ^ (lq << 2)) + ks) & 15) | (lq << 4);
        af2[ks] = *(const bf16x8*)&A2p[ks * 512 + slot * 8];
      }
      __syncthreads();  // all reads of A2p complete before aliased C2 writes
#pragma unroll
      for (int nt = 0; nt < 2; ++nt) {
        int g = w * 2 + nt;
        const u16* bb = WmT + (size_t)(g * 16 + ln) * 384 + lq * 8;
        f32x4 acc = {0.f, 0.f, 0.f, 0.f};
#pragma unroll
        for (int ks = 0; ks < 12; ++ks)
          acc = __builtin_amdgcn_mfma_f32_16x16x32_bf16(
              af2[ks], *(const bf16x8*)(bb + ks * 32), acc, 0, 0, 0);
        int col = g * 16 + ln;
        float bcol = bm_l[col];
#pragma unroll
        for (int rr = 0; rr < 4; ++rr) C2[(lq * 4 + rr) * 132 + col] = acc[rr] + bcol;
      }
    }
    __syncthreads();

    // ---- LN128 + scatter (unsorted dst -> uncontended atomics) ----
    {
      for (int rw = w; rw < 16; rw += 4) {
        float v0 = C2[rw * 132 + l], v1 = C2[rw * 132 + l + 64];
        float sa = v0 + v1, s2a = v0 * v0 + v1 * v1;
#pragma unroll
        for (int off2 = 32; off2 > 0; off2 >>= 1) {
          sa += __shfl_down(sa, off2); s2a += __shfl_down(s2a, off2);
        }
        sa = __shfl(sa, 0); s2a = __shfl(s2a, 0);
        float mean = sa * (1.f / CDIM);
        float rstd = rsqrtf(s2a * (1.f / CDIM) - mean * mean + 1e-5f);
        int h = rw >> 3, e = rw & 7;
        int dstn = did16[s * 8 + e];
        float o0 = (v0 - mean) * rstd * lmg[l] + lmb[l];
        float o1 = (v1 - mean) * rstd * lmg[l + 64] + lmb[l + 64];
        atomicAdd(&agg[(size_t)dstn * HCDIM + h * CDIM + l], o0);
        atomicAdd(&agg[(size_t)dstn * HCDIM + h * CDIM + l + 64], o1);
      }
    }
    __syncthreads();
  }
}

// ---------------- fused BN(from sums) + SiLU + skip(from qkp) ----------------
__global__ void bn_silu_skip_kernel(
    const float* __restrict__ o, const u16* __restrict__ qkp,
    const float* __restrict__ cs, const float* __restrict__ cs2,
    const float* __restrict__ g, const float* __restrict__ b,
    float* __restrict__ nf, u16* __restrict__ nfb) {
  int idx = blockIdx.x * blockDim.x + threadIdx.x;
  if (idx >= N_NODES * CDIM) return;
  int c = idx & (CDIM - 1);
  int n = idx >> 7;
  float m = cs[c] * (1.f / N_NODES);
  float var = cs2[c] * (1.f / N_NODES) - m * m;
  float rstd = rsqrtf(var + 1e-5f);
  float x = (o[idx] - m) * rstd * g[c] + b[c];
  float sig = 1.f / (1.f + expf(-x));
  float skipv = bf2f(qkp[(size_t)n * QKPW + 2048 + c]);
  float val = x * sig + skipv;
  nf[idx] = val;
  nfb[idx] = f2bf(val);
}

// ---------------- fused mean-pool + feats (batch is sorted) ------------------
__global__ __launch_bounds__(256) void poolfeats_kernel(
    const float* __restrict__ nf, const int* __restrict__ batch,
    const float* __restrict__ pge, const float* __restrict__ cse,
    float* __restrict__ feats) {
  const int b = blockIdx.x, tid = threadIdx.x;
  int lo = 0, hi = N_NODES;
  {
    int L = 0, R = N_NODES;
    while (L < R) { int m2 = (L + R) >> 1; if (batch[m2] < b) L = m2 + 1; else R = m2; }
    lo = L;
    L = lo; R = N_NODES;
    while (L < R) { int m2 = (L + R) >> 1; if (batch[m2] <= b) L = m2 + 1; else R = m2; }
    hi = L;
  }
  __shared__ float sacc[2][128];
  const int half = tid >> 7, c = tid & 127;
  float s = 0.f;
  for (int n = lo + half; n < hi; n += 2) s += nf[(size_t)n * CDIM + c];
  sacc[half][c] = s;
  __syncthreads();
  float cntf = fmaxf((float)(hi - lo), 1.f);
  if (tid < 128) feats[b * 167 + tid] = (sacc[0][tid] + sacc[1][tid]) / cntf;
  else if (tid < 160) feats[b * 167 + 128 + (tid - 128)] = pge[b * 32 + (tid - 128)];
  else if (tid < 167) feats[b * 167 + 160 + (tid - 160)] = cse[b * 7 + (tid - 160)];
}

// ---------------- fused fc + out ---------------------------------------------
__global__ __launch_bounds__(256) void fcout_kernel(
    const float* __restrict__ feats, const float* __restrict__ fc_W,
    const float* __restrict__ fc_b, const float* __restrict__ ow,
    const float* __restrict__ ob, float* __restrict__ out) {
  const int b = blockIdx.x, tid = threadIdx.x;
  __shared__ float sf[167];
  if (tid < 167) sf[tid] = feats[b * 167 + tid];
  __syncthreads();
  float acc0 = fc_b[tid], acc1 = fc_b[tid + 256];
  for (int k = 0; k < 167; ++k) {
    float fv = sf[k];
    acc0 += fv * fc_W[(size_t)k * 512 + tid];
    acc1 += fv * fc_W[(size_t)k * 512 + tid + 256];
  }
  float h0 = acc0 / (1.f + expf(-acc0));
  float h1 = acc1 / (1.f + expf(-acc1));
  float s = h0 * ow[tid] + h1 * ow[tid + 256];
  __shared__ float red[4];
#pragma unroll
  for (int off = 32; off > 0; off >>= 1) s += __shfl_down(s, off);
  if ((tid & 63) == 0) red[tid >> 6] = s;
  __syncthreads();
  if (tid == 0) out[b] = red[0] + red[1] + red[2] + red[3] + ob[0];
}

// ---------------- launch -----------------------------------------------------
extern "C" void kernel_launch(void* const* d_in, const int* in_sizes, int n_in,
                              void* d_out, int out_size, void* d_ws, size_t ws_size,
                              hipStream_t stream) {
  const float* x         = (const float*)d_in[0];
  const float* edge_attr = (const float*)d_in[1];
  const float* pge       = (const float*)d_in[2];
  const float* cse       = (const float*)d_in[3];
  const int*   ei        = (const int*)d_in[4];
  const int*   batch     = (const int*)d_in[5];
  const float* atom_W    = (const float*)d_in[6];
  const float* atom_b    = (const float*)d_in[7];
  const float* edge_W    = (const float*)d_in[8];
  const float* edge_b    = (const float*)d_in[9];
  const float* Wq        = (const float*)d_in[10];
  const float* bq        = (const float*)d_in[11];
  const float* Wk        = (const float*)d_in[12];
  const float* bk        = (const float*)d_in[13];
  const float* Wv        = (const float*)d_in[14];
  const float* bv        = (const float*)d_in[15];
  const float* We        = (const float*)d_in[16];
  const float* Wmu       = (const float*)d_in[17];
  const float* bmu       = (const float*)d_in[18];
  const float* Wm        = (const float*)d_in[19];
  const float* bm        = (const float*)d_in[20];
  const float* ln_m_g    = (const float*)d_in[21];
  const float* ln_m_b    = (const float*)d_in[22];
  const float* ln_a_g    = (const float*)d_in[23];
  const float* ln_a_b    = (const float*)d_in[24];
  const float* Wc        = (const float*)d_in[25];
  const float* bc        = (const float*)d_in[26];
  const float* bn_g      = (const float*)d_in[27];
  const float* bn_b      = (const float*)d_in[28];
  const float* Wskip     = (const float*)d_in[29];
  const float* bskip     = (const float*)d_in[30];
  const float* fc_W      = (const float*)d_in[31];
  const float* fc_b      = (const float*)d_in[32];
  const float* out_W     = (const float*)d_in[33];
  const float* out_b     = (const float*)d_in[34];

  float* ws = (float*)d_ws;
  size_t off = 0;
  float* nf    = ws + off; off += (size_t)N_NODES * CDIM;
  float* agg   = ws + off; off += (size_t)N_NODES * HCDIM;
  float* o     = ws + off; off += (size_t)N_NODES * CDIM;
  float* cbv   = ws + off; off += 768;
  float* ball  = ws + off; off += QKPW;
  float* csum  = ws + off; off += CDIM;
  float* csum2 = ws + off; off += CDIM;
  float* feats = ws + off; off += (size_t)N_GRAPH * 167;
  u16* efb   = (u16*)(ws + off); off += (size_t)N_EDGES * 64;       // E*128 u16
  u16* WcT   = (u16*)(ws + off); off += 65536;                      // 1024*128 u16
  u16* WmTb  = (u16*)(ws + off); off += 24576;                      // 128*384 u16
  u16* nfb   = (u16*)(ws + off); off += (size_t)N_NODES * 64;       // N*128 u16
  u16* qkp   = (u16*)(ws + off); off += (size_t)N_NODES * (QKPW/2); // N*2176 u16
  u16* WallT = (u16*)(ws + off); off += (size_t)QKPW * 64;          // 2176*128 u16
  u16* WcTw  = (u16*)(ws + off); off += 16384;                      // 128*256 u16
  u16* xpad  = (u16*)(ws + off); off += (size_t)N_NODES * 48;       // N*96 u16
  u16* epad  = (u16*)(ws + off); off += (size_t)N_EDGES * 32;       // E*64 u16
  u16* atomWT= (u16*)(ws + off); off += 6144;                       // 128*96 u16
  u16* WeT2  = (u16*)(ws + off); off += 4096;                       // 128*64 u16

  // ---- one-time: pack inputs, initial MFMA GEMMs ----
  pack_init_kernel<<<dim3(256, 4), 256, 0, stream>>>(x, edge_attr, atom_W, edge_W,
                                                     xpad, epad, atomWT, WeT2);
  mfma_gemm_kernel<0, 0, 0><<<dim3(2, 79), 256, 0, stream>>>(
      xpad, atomWT, atom_b, nf, nfb, nullptr, nullptr, N_NODES, 96, CDIM);
  mfma_gemm_kernel<1, 0, 0><<<dim3(2, 782), 256, 0, stream>>>(
      epad, WeT2, edge_b, efb, nullptr, nullptr, nullptr, N_EDGES, 64, CDIM);

  for (int i = 0; i < 2; ++i) {
    prep_kernel<<<dim3(1800), 256, 0, stream>>>(
        Wv + (size_t)i * CDIM * HCDIM, We + (size_t)i * CDIM * HCDIM,
        Wmu + (size_t)i * C3DIM * C3DIM,
        Wq + (size_t)i * CDIM * HCDIM, Wk + (size_t)i * CDIM * HCDIM,
        Wc + (size_t)i * HCDIM * CDIM, Wskip + (size_t)i * CDIM * CDIM,
        Wm + (size_t)i * C3DIM * CDIM, bmu + i * C3DIM, bv + i * HCDIM,
        bq + i * HCDIM, bk + i * HCDIM, bskip + i * CDIM,
        WallT, WcT, WcTw, WmTb, cbv, ball, agg, csum, csum2);

    // qkp = nfb @ [Wq|Wk|WP12|Wskip]  (N=2176, bf16 out)
    mfma_gemm_kernel<1, 0, 0><<<dim3(QKPW / 64, 79), 256, 0, stream>>>(
        nfb, WallT, ball, qkp, nullptr, nullptr, nullptr, N_NODES, CDIM, QKPW);

    edge_kernel<<<dim3(N_EDGES / 16), dim3(256), 0, stream>>>(
        qkp, efb, ei, WcT, cbv,
        ln_a_g + i * C3DIM, ln_a_b + i * C3DIM,
        WmTb, bm + i * CDIM,
        ln_m_g + i * CDIM, ln_m_b + i * CDIM, agg, N_EDGES);

    // o = agg @ Wc + bc  (A fp32 converted in-register; BN stats fused)
    mfma_gemm_kernel<0, 1, 1><<<dim3(2, 79), 256, 0, stream>>>(
        agg, WcTw, bc + i * CDIM, o, nullptr, csum, csum2, N_NODES, HCDIM, CDIM);

    bn_silu_skip_kernel<<<dim3((N_NODES * CDIM + 255) / 256), dim3(256), 0, stream>>>(
        o, qkp, csum, csum2, bn_g + i * CDIM, bn_b + i * CDIM, nf, nfb);
  }

  poolfeats_kernel<<<dim3(N_GRAPH), 256, 0, stream>>>(nf, batch, pge, cse, feats);
  fcout_kernel<<<dim3(N_GRAPH), 256, 0, stream>>>(feats, fc_W, fc_b, out_W, out_b,
                                                  (float*)d_out);
}

// Round 11
// 1170.962 us; speedup vs baseline: 1.6411x; 1.0398x over previous
//
#include <hip/hip_runtime.h>
#include <math.h>

#define N_NODES 10000
#define N_EDGES 100000
#define N_GRAPH 64
#define CDIM 128
#define HCDIM 256
#define C3DIM 384
#define QKPW 2176   // qkp row width: [q(256)|k(256)|P12(1536)|skip(128)]

typedef unsigned short u16;
typedef __attribute__((ext_vector_type(8))) short bf16x8;
typedef __attribute__((ext_vector_type(4))) float f32x4;

__device__ __forceinline__ u16 f2bf(float f) {
  union { float f; unsigned int u; } x; x.f = f;
  unsigned int u = x.u + 0x7fffu + ((x.u >> 16) & 1u);
  return (u16)(u >> 16);
}
__device__ __forceinline__ float bf2f(u16 h) {
  union { unsigned int u; float f; } x; x.u = ((unsigned int)h) << 16;
  return x.f;
}

// ---------------- MFMA dense GEMM ------------------------------------------
template<int OUT_BF16, int DO_STATS, int A_F32>
__global__ __launch_bounds__(256) void mfma_gemm_kernel(
    const void* __restrict__ Ain, const u16* __restrict__ WT,
    const float* __restrict__ bias, void* __restrict__ Y,
    u16* __restrict__ Ymirror, float* __restrict__ cs, float* __restrict__ cs2,
    int M, int K, int N) {
  const int tid = threadIdx.x;
  const int w = tid >> 6, l = tid & 63;
  const int lq = l >> 4, ln = l & 15;
  const int bm = blockIdx.y * 128, bn = blockIdx.x * 64;
  int ra = bm + w * 32 + ln;      if (ra > M - 1) ra = M - 1;
  int rb = bm + w * 32 + 16 + ln; if (rb > M - 1) rb = M - 1;
  f32x4 acc[2][4];
#pragma unroll
  for (int g = 0; g < 2; ++g)
#pragma unroll
    for (int nt = 0; nt < 4; ++nt) acc[g][nt] = {0.f, 0.f, 0.f, 0.f};
  for (int k0 = 0; k0 < K; k0 += 32) {
    bf16x8 a0, a1;
    if (A_F32) {
      const float* Af = (const float*)Ain;
      f32x4 p0 = *(const f32x4*)&Af[(size_t)ra * K + k0 + lq * 8];
      f32x4 p1 = *(const f32x4*)&Af[(size_t)ra * K + k0 + lq * 8 + 4];
      f32x4 p2 = *(const f32x4*)&Af[(size_t)rb * K + k0 + lq * 8];
      f32x4 p3 = *(const f32x4*)&Af[(size_t)rb * K + k0 + lq * 8 + 4];
#pragma unroll
      for (int j = 0; j < 4; ++j) {
        a0[j] = (short)f2bf(p0[j]); a0[4 + j] = (short)f2bf(p1[j]);
        a1[j] = (short)f2bf(p2[j]); a1[4 + j] = (short)f2bf(p3[j]);
      }
    } else {
      const u16* Ab = (const u16*)Ain;
      a0 = *(const bf16x8*)&Ab[(size_t)ra * K + k0 + lq * 8];
      a1 = *(const bf16x8*)&Ab[(size_t)rb * K + k0 + lq * 8];
    }
#pragma unroll
    for (int nt = 0; nt < 4; ++nt) {
      bf16x8 b = *(const bf16x8*)&WT[(size_t)(bn + nt * 16 + ln) * K + k0 + lq * 8];
      acc[0][nt] = __builtin_amdgcn_mfma_f32_16x16x32_bf16(a0, b, acc[0][nt], 0, 0, 0);
      acc[1][nt] = __builtin_amdgcn_mfma_f32_16x16x32_bf16(a1, b, acc[1][nt], 0, 0, 0);
    }
  }
#pragma unroll
  for (int g = 0; g < 2; ++g) {
    int rowbase = bm + w * 32 + g * 16 + lq * 4;
#pragma unroll
    for (int nt = 0; nt < 4; ++nt) {
      int gn = bn + nt * 16 + ln;
      float bv = bias ? bias[gn] : 0.f;
#pragma unroll
      for (int r = 0; r < 4; ++r) {
        int gm = rowbase + r;
        if (gm < M) {
          float val = acc[g][nt][r] + bv;
          if (OUT_BF16) ((u16*)Y)[(size_t)gm * N + gn] = f2bf(val);
          else          ((float*)Y)[(size_t)gm * N + gn] = val;
          if (Ymirror)  Ymirror[(size_t)gm * N + gn] = f2bf(val);
        }
      }
    }
  }
  if (DO_STATS) {
#pragma unroll
    for (int nt = 0; nt < 4; ++nt) {
      int gn = bn + nt * 16 + ln;
      float bv = bias ? bias[gn] : 0.f;
      float s = 0.f, s2 = 0.f;
#pragma unroll
      for (int g = 0; g < 2; ++g) {
        int rowbase = bm + w * 32 + g * 16 + lq * 4;
#pragma unroll
        for (int r = 0; r < 4; ++r) {
          if (rowbase + r < M) {
            float v = acc[g][nt][r] + bv;
            s += v; s2 += v * v;
          }
        }
      }
      s += __shfl_xor(s, 16); s2 += __shfl_xor(s2, 16);
      s += __shfl_xor(s, 32); s2 += __shfl_xor(s2, 32);
      if (lq == 0) { atomicAdd(&cs[gn], s); atomicAdd(&cs2[gn], s2); }
    }
  }
}

// ---------------- init packs: xpad/epad/atomWT/WeT2 (z-sliced) ---------------
__global__ void pack_init_kernel(
    const float* __restrict__ x, const float* __restrict__ ea,
    const float* __restrict__ atom_W, const float* __restrict__ edge_W,
    u16* __restrict__ xpad, u16* __restrict__ epad,
    u16* __restrict__ atomWT, u16* __restrict__ WeT2) {
  int z = blockIdx.y;
  int idx0 = blockIdx.x * 256 + threadIdx.x;
  const int stride = 256 * 256;
  if (z == 0) {
    for (int idx = idx0; idx < N_NODES * 96; idx += stride) {
      int n = idx / 96, k = idx - n * 96;
      xpad[idx] = (k < 92) ? f2bf(x[(size_t)n * 92 + k]) : (u16)0;
    }
  } else if (z == 1) {
    for (int idx = idx0; idx < N_EDGES * 64; idx += stride) {
      int e = idx >> 6, k = idx & 63;
      epad[idx] = (k < 50) ? f2bf(ea[(size_t)e * 50 + k]) : (u16)0;
    }
  } else if (z == 2) {
    if (idx0 < 128 * 96) { int n = idx0 / 96, k = idx0 - n * 96;
      atomWT[idx0] = (k < 92) ? f2bf(atom_W[(size_t)k * 128 + n]) : (u16)0; }
  } else {
    if (idx0 < 128 * 64) { int n = idx0 >> 6, k = idx0 & 63;
      WeT2[idx0] = (k < 50) ? f2bf(edge_W[(size_t)k * 128 + n]) : (u16)0; }
  }
}

// ---------------- merged prep kernel ----------------------------------------
__global__ __launch_bounds__(256) void prep_kernel(
    const float* __restrict__ Wv, const float* __restrict__ We_l,
    const float* __restrict__ Wmu,
    const float* __restrict__ Wq, const float* __restrict__ Wk,
    const float* __restrict__ Wc, const float* __restrict__ Wsk,
    const float* __restrict__ Wm_l, const float* __restrict__ bmu,
    const float* __restrict__ bv_l,
    const float* __restrict__ bq_l, const float* __restrict__ bk_l,
    const float* __restrict__ bsk_l,
    u16* __restrict__ WallT, u16* __restrict__ WcT, u16* __restrict__ WcTw,
    u16* __restrict__ WmTb, float* __restrict__ cbv, float* __restrict__ ball,
    float* __restrict__ agg, float* __restrict__ cs, float* __restrict__ cs2) {
  __shared__ float As[16][68];
  __shared__ float Bs[16][65];
  const int b = blockIdx.x;
  const int tid = threadIdx.x;
  if (b < 72) {
    const int zc = b / 12, rem = b % 12;
    const int by = rem / 6, bx = rem % 6;
    const float* Ap; const float* Bp; u16* Cp; int colbase;
    if (zc < 4) {
      int part = zc >> 1, h = zc & 1;
      Ap = Wv + h * 128; Bp = Wmu + part * 128 * 384;
      Cp = WallT; colbase = 512 + part * 768 + h * 384;
    } else {
      int h = zc - 4;
      Ap = We_l + h * 128; Bp = Wmu + 256 * 384;
      Cp = WcT; colbase = 256 + h * 384;
    }
    const int bm = by * 64, bn = bx * 64;
    const int tx = tid & 15, ty = tid >> 4;
    float acc[4][4] = {};
    for (int k0 = 0; k0 < 128; k0 += 16) {
#pragma unroll
      for (int i = 0; i < 4; ++i) {
        int l = tid + i * 256;
        int kk = l & 15, m = l >> 4;
        As[kk][m] = Ap[(size_t)(bm + m) * 256 + k0 + kk];
      }
#pragma unroll
      for (int i = 0; i < 4; ++i) {
        int l = tid + i * 256;
        int n = l & 63, kk = l >> 6;
        Bs[kk][n] = Bp[(size_t)(k0 + kk) * 384 + bn + n];
      }
      __syncthreads();
#pragma unroll
      for (int kk = 0; kk < 16; ++kk) {
        float a[4], bb[4];
#pragma unroll
        for (int i = 0; i < 4; ++i) a[i] = As[kk][ty * 4 + i];
#pragma unroll
        for (int j = 0; j < 4; ++j) bb[j] = Bs[kk][tx * 4 + j];
#pragma unroll
        for (int i = 0; i < 4; ++i)
#pragma unroll
          for (int j = 0; j < 4; ++j) acc[i][j] += a[i] * bb[j];
      }
      __syncthreads();
    }
#pragma unroll
    for (int i = 0; i < 4; ++i) {
      int gk = bm + ty * 4 + i;
#pragma unroll
      for (int j = 0; j < 4; ++j) {
        int gcol = colbase + bn + tx * 4 + j;
        Cp[(size_t)gcol * 128 + gk] = f2bf(acc[i][j]);
      }
    }
    return;
  }
  const int pb = b - 72;
  const int z = pb / 192;
  const int idx = (pb % 192) * 256 + tid;
  if (z == 0) {
    if (idx < 32768) { int col = idx >> 7, kk = idx & 127;
      WallT[(size_t)col * 128 + kk] = f2bf(Wq[(size_t)kk * 256 + col]); }
  } else if (z == 1) {
    if (idx < 32768) { int col = idx >> 7, kk = idx & 127;
      WallT[(size_t)(256 + col) * 128 + kk] = f2bf(Wk[(size_t)kk * 256 + col]); }
  } else if (z == 2) {
    if (idx < 32768) { int col = idx >> 8, kk = idx & 255;
      WcTw[(size_t)col * 256 + kk] = f2bf(Wc[(size_t)kk * 128 + col]); }
  } else if (z == 3) {
    if (idx < 16384) { int col = idx >> 7, kk = idx & 127;
      WallT[(size_t)(2048 + col) * 128 + kk] = f2bf(Wsk[(size_t)kk * 128 + col]); }
  } else if (z == 4) {
    if (idx < 49152) { int col = idx / 384, kk = idx - col * 384;
      WmTb[idx] = f2bf(Wm_l[(size_t)kk * 128 + col]); }
  } else if (z == 5) {
    if (idx < 768) {
      int h2 = idx / 384, g = idx - h2 * 384;
      float s = bmu[g];
      for (int d = 0; d < 128; ++d)
        s += bv_l[h2 * 128 + d] * (Wmu[(size_t)d * 384 + g] + Wmu[(size_t)(128 + d) * 384 + g]);
      cbv[idx] = s;
    }
  } else if (z == 6) {
    if (idx < QKPW) {
      float v = 0.f;
      if (idx < 256) v = bq_l[idx];
      else if (idx < 512) v = bk_l[idx - 256];
      else if (idx >= 2048) v = bsk_l[idx - 2048];
      ball[idx] = v;
    }
  } else if (z == 7) {
    for (int p = idx; p < N_NODES * HCDIM; p += 192 * 256) agg[p] = 0.f;
    if (idx < 128) { cs[idx] = 0.f; cs2[idx] = 0.f; }
  } else {
    if (idx < 32768) { int col = idx >> 7, kk = idx & 127;
      WcT[(size_t)col * 128 + kk] = f2bf(We_l[(size_t)kk * 256 + col]); }
  }
}

// ---------------- fused per-edge kernel (MFMA, 16 edges x 1 head per block) --
// blockIdx: h = bid&1, e0 = (bid>>1)*16. Rows r = edge index (0..15).
// C1[r][0:128] = sea_h, C1[r][128:512] = Pe_h. 4 barriers; 5 blocks/CU.
#define C1S 520
__global__ __launch_bounds__(256, 5) void edge_kernel(
    const u16* __restrict__ qkp, const u16* __restrict__ efb,
    const int* __restrict__ ei, const u16* __restrict__ WcT,
    const float* __restrict__ cbv,
    const float* __restrict__ lag, const float* __restrict__ lab,
    const u16* __restrict__ WmT, const float* __restrict__ bm_l,
    const float* __restrict__ lmg, const float* __restrict__ lmb,
    float* __restrict__ agg, int E) {
  __shared__ __align__(16) u16 C1[16 * C1S];
  __shared__ __align__(16) u16 A2p[12 * 512];   // aliased as C2 float[16][132]
  __shared__ int did16[16];
  float* C2 = (float*)A2p;
  const int tid = threadIdx.x;
  const int h = blockIdx.x & 1;
  const int e0 = (blockIdx.x >> 1) * 16;
  const int w = tid >> 6, l = tid & 63;
  const int lq = l >> 4, ln = l & 15;
  const float scale = 0.051031036307982884f;  // 1/sqrt(384)

  if (tid < 16) did16[tid] = ei[E + e0 + tid];

  const int r = tid >> 4, lx = tid & 15;   // row = edge, 16 lanes per row

  // ---- Prefetch all random gathers (one head) ----
  bf16x8 qv, kdv, ksv, pdv[3], psv[3];
  {
    int edge = e0 + r;
    int dstn = ei[E + edge], srcn = ei[edge];
    const u16* db = qkp + (size_t)dstn * QKPW;
    const u16* sb = qkp + (size_t)srcn * QKPW;
    qv  = *(const bf16x8*)&db[h * 128 + lx * 8];
    kdv = *(const bf16x8*)&db[256 + h * 128 + lx * 8];
    ksv = *(const bf16x8*)&sb[256 + h * 128 + lx * 8];
#pragma unroll
    for (int p = 0; p < 3; ++p) {
      pdv[p] = *(const bf16x8*)&db[512 + h * 384 + p * 128 + lx * 8];
      psv[p] = *(const bf16x8*)&sb[512 + 768 + h * 384 + p * 128 + lx * 8];
    }
  }

  // ---- GEMM1: C1[16][512] = efb rows @ WcT head-h columns ----
  {
    bf16x8 afr[4];
    const u16* ab = efb + (size_t)(e0 + ln) * 128 + lq * 8;
#pragma unroll
    for (int ks = 0; ks < 4; ++ks) afr[ks] = *(const bf16x8*)(ab + ks * 32);
#pragma unroll 2
    for (int nt = 0; nt < 8; ++nt) {
      int col0 = (w * 8 + nt) * 16;               // 0..496, step 16
      int wc = (col0 < 128) ? h * 128 + col0 : 256 + h * 384 + (col0 - 128);
      const u16* bb = WcT + (size_t)(wc + ln) * 128 + lq * 8;
      f32x4 acc = {0.f, 0.f, 0.f, 0.f};
#pragma unroll
      for (int ks = 0; ks < 4; ++ks)
        acc = __builtin_amdgcn_mfma_f32_16x16x32_bf16(
            afr[ks], *(const bf16x8*)(bb + ks * 32), acc, 0, 0, 0);
      int col = col0 + ln;
#pragma unroll
      for (int rr = 0; rr < 4; ++rr) C1[(lq * 4 + rr) * C1S + col] = f2bf(acc[rr]);
    }
  }
  __syncthreads();

  // ---- Phase A+4 fused: alpha -> LN384 -> gate (regs) -> t -> A2p ----
  {
    bf16x8 sea = *(const bf16x8*)&C1[r * C1S + lx * 8];
    float a0[8], a1[8], a2[8];
    float sacc = 0.f, s2acc = 0.f;
#pragma unroll
    for (int j = 0; j < 8; ++j) {
      float qf = bf2f((u16)qv[j]);
      float x0 = qf * bf2f((u16)kdv[j]) * scale;
      float x1 = qf * bf2f((u16)ksv[j]) * scale;
      float x2 = qf * bf2f((u16)sea[j]) * scale;
      a0[j] = x0; a1[j] = x1; a2[j] = x2;
      sacc += x0 + x1 + x2;
      s2acc += x0 * x0 + x1 * x1 + x2 * x2;
    }
#pragma unroll
    for (int mm = 1; mm < 16; mm <<= 1) {
      sacc += __shfl_xor(sacc, mm); s2acc += __shfl_xor(s2acc, mm);
    }
    float mean = sacc * (1.f / C3DIM);
    float rstd = rsqrtf(s2acc * (1.f / C3DIM) - mean * mean + 1e-5f);
#pragma unroll
    for (int p = 0; p < 3; ++p) {
      const float* lg = lag + p * 128 + lx * 8;
      const float* lb = lab + p * 128 + lx * 8;
      f32x4 g0 = *(const f32x4*)lg, g1 = *(const f32x4*)(lg + 4);
      f32x4 b0 = *(const f32x4*)lb, b1 = *(const f32x4*)(lb + 4);
      f32x4 c0 = *(const f32x4*)&cbv[h * 384 + p * 128 + lx * 8];
      f32x4 c1 = *(const f32x4*)&cbv[h * 384 + p * 128 + lx * 8 + 4];
      bf16x8 pe = *(const bf16x8*)&C1[r * C1S + 128 + p * 128 + lx * 8];
      bf16x8 outv;
#pragma unroll
      for (int j = 0; j < 8; ++j) {
        float av = p == 0 ? a0[j] : (p == 1 ? a1[j] : a2[j]);
        float gg = j < 4 ? g0[j] : g1[j - 4];
        float bb2 = j < 4 ? b0[j] : b1[j - 4];
        float cbj = j < 4 ? c0[j] : c1[j - 4];
        float z = (av - mean) * rstd * gg + bb2;
        float gate = 1.f / (1.f + expf(-z));
        float t = (bf2f((u16)pe[j]) + bf2f((u16)pdv[p][j]) +
                   bf2f((u16)psv[p][j]) + cbj) * gate;
        outv[j] = (short)f2bf(t);
      }
      int ks = p * 4 + (lx >> 2), qq = lx & 3;
      int slot = (((r ^ (qq << 2)) + ks) & 15) | (qq << 4);
      *(bf16x8*)&A2p[ks * 512 + slot * 8] = outv;
    }
  }
  __syncthreads();

  // ---- GEMM2: m[16][128] = A2 @ WmT ----
  {
    bf16x8 af2[12];
#pragma unroll
    for (int ks = 0; ks < 12; ++ks) {
      int slot = (((ln ^ (lq << 2)) + ks) & 15) | (lq << 4);
      af2[ks] = *(const bf16x8*)&A2p[ks * 512 + slot * 8];
    }
    __syncthreads();  // all reads of A2p complete before aliased C2 writes
#pragma unroll
    for (int nt = 0; nt < 2; ++nt) {
      int g = w * 2 + nt;
      const u16* bb = WmT + (size_t)(g * 16 + ln) * 384 + lq * 8;
      f32x4 acc = {0.f, 0.f, 0.f, 0.f};
#pragma unroll
      for (int ks = 0; ks < 12; ++ks)
        acc = __builtin_amdgcn_mfma_f32_16x16x32_bf16(
            af2[ks], *(const bf16x8*)(bb + ks * 32), acc, 0, 0, 0);
      int col = g * 16 + ln;
      float bcol = bm_l[col];
#pragma unroll
      for (int rr = 0; rr < 4; ++rr) C2[(lq * 4 + rr) * 132 + col] = acc[rr] + bcol;
    }
  }
  __syncthreads();

  // ---- LN128 + scatter (unsorted dst -> uncontended atomics) ----
  {
    for (int rw = w; rw < 16; rw += 4) {
      float v0 = C2[rw * 132 + l], v1 = C2[rw * 132 + l + 64];
      float sa = v0 + v1, s2a = v0 * v0 + v1 * v1;
#pragma unroll
      for (int off2 = 32; off2 > 0; off2 >>= 1) {
        sa += __shfl_down(sa, off2); s2a += __shfl_down(s2a, off2);
      }
      sa = __shfl(sa, 0); s2a = __shfl(s2a, 0);
      float mean = sa * (1.f / CDIM);
      float rstd = rsqrtf(s2a * (1.f / CDIM) - mean * mean + 1e-5f);
      int dstn = did16[rw];
      float o0 = (v0 - mean) * rstd * lmg[l] + lmb[l];
      float o1 = (v1 - mean) * rstd * lmg[l + 64] + lmb[l + 64];
      atomicAdd(&agg[(size_t)dstn * HCDIM + h * CDIM + l], o0);
      atomicAdd(&agg[(size_t)dstn * HCDIM + h * CDIM + l + 64], o1);
    }
  }
}

// ---------------- fused BN(from sums) + SiLU + skip(from qkp) ----------------
__global__ void bn_silu_skip_kernel(
    const float* __restrict__ o, const u16* __restrict__ qkp,
    const float* __restrict__ cs, const float* __restrict__ cs2,
    const float* __restrict__ g, const float* __restrict__ b,
    float* __restrict__ nf, u16* __restrict__ nfb) {
  int idx = blockIdx.x * blockDim.x + threadIdx.x;
  if (idx >= N_NODES * CDIM) return;
  int c = idx & (CDIM - 1);
  int n = idx >> 7;
  float m = cs[c] * (1.f / N_NODES);
  float var = cs2[c] * (1.f / N_NODES) - m * m;
  float rstd = rsqrtf(var + 1e-5f);
  float x = (o[idx] - m) * rstd * g[c] + b[c];
  float sig = 1.f / (1.f + expf(-x));
  float skipv = bf2f(qkp[(size_t)n * QKPW + 2048 + c]);
  float val = x * sig + skipv;
  nf[idx] = val;
  nfb[idx] = f2bf(val);
}

// ---------------- fused mean-pool + feats (batch is sorted) ------------------
__global__ __launch_bounds__(256) void poolfeats_kernel(
    const float* __restrict__ nf, const int* __restrict__ batch,
    const float* __restrict__ pge, const float* __restrict__ cse,
    float* __restrict__ feats) {
  const int b = blockIdx.x, tid = threadIdx.x;
  int lo = 0, hi = N_NODES;
  {
    int L = 0, R = N_NODES;
    while (L < R) { int m2 = (L + R) >> 1; if (batch[m2] < b) L = m2 + 1; else R = m2; }
    lo = L;
    L = lo; R = N_NODES;
    while (L < R) { int m2 = (L + R) >> 1; if (batch[m2] <= b) L = m2 + 1; else R = m2; }
    hi = L;
  }
  __shared__ float sacc[2][128];
  const int half = tid >> 7, c = tid & 127;
  float s = 0.f;
  for (int n = lo + half; n < hi; n += 2) s += nf[(size_t)n * CDIM + c];
  sacc[half][c] = s;
  __syncthreads();
  float cntf = fmaxf((float)(hi - lo), 1.f);
  if (tid < 128) feats[b * 167 + tid] = (sacc[0][tid] + sacc[1][tid]) / cntf;
  else if (tid < 160) feats[b * 167 + 128 + (tid - 128)] = pge[b * 32 + (tid - 128)];
  else if (tid < 167) feats[b * 167 + 160 + (tid - 160)] = cse[b * 7 + (tid - 160)];
}

// ---------------- fused fc + out ---------------------------------------------
__global__ __launch_bounds__(256) void fcout_kernel(
    const float* __restrict__ feats, const float* __restrict__ fc_W,
    const float* __restrict__ fc_b, const float* __restrict__ ow,
    const float* __restrict__ ob, float* __restrict__ out) {
  const int b = blockIdx.x, tid = threadIdx.x;
  __shared__ float sf[167];
  if (tid < 167) sf[tid] = feats[b * 167 + tid];
  __syncthreads();
  float acc0 = fc_b[tid], acc1 = fc_b[tid + 256];
  for (int k = 0; k < 167; ++k) {
    float fv = sf[k];
    acc0 += fv * fc_W[(size_t)k * 512 + tid];
    acc1 += fv * fc_W[(size_t)k * 512 + tid + 256];
  }
  float h0 = acc0 / (1.f + expf(-acc0));
  float h1 = acc1 / (1.f + expf(-acc1));
  float s = h0 * ow[tid] + h1 * ow[tid + 256];
  __shared__ float red[4];
#pragma unroll
  for (int off = 32; off > 0; off >>= 1) s += __shfl_down(s, off);
  if ((tid & 63) == 0) red[tid >> 6] = s;
  __syncthreads();
  if (tid == 0) out[b] = red[0] + red[1] + red[2] + red[3] + ob[0];
}

// ---------------- launch -----------------------------------------------------
extern "C" void kernel_launch(void* const* d_in, const int* in_sizes, int n_in,
                              void* d_out, int out_size, void* d_ws, size_t ws_size,
                              hipStream_t stream) {
  const float* x         = (const float*)d_in[0];
  const float* edge_attr = (const float*)d_in[1];
  const float* pge       = (const float*)d_in[2];
  const float* cse       = (const float*)d_in[3];
  const int*   ei        = (const int*)d_in[4];
  const int*   batch     = (const int*)d_in[5];
  const float* atom_W    = (const float*)d_in[6];
  const float* atom_b    = (const float*)d_in[7];
  const float* edge_W    = (const float*)d_in[8];
  const float* edge_b    = (const float*)d_in[9];
  const float* Wq        = (const float*)d_in[10];
  const float* bq        = (const float*)d_in[11];
  const float* Wk        = (const float*)d_in[12];
  const float* bk        = (const float*)d_in[13];
  const float* Wv        = (const float*)d_in[14];
  const float* bv        = (const float*)d_in[15];
  const float* We        = (const float*)d_in[16];
  const float* Wmu       = (const float*)d_in[17];
  const float* bmu       = (const float*)d_in[18];
  const float* Wm        = (const float*)d_in[19];
  const float* bm        = (const float*)d_in[20];
  const float* ln_m_g    = (const float*)d_in[21];
  const float* ln_m_b    = (const float*)d_in[22];
  const float* ln_a_g    = (const float*)d_in[23];
  const float* ln_a_b    = (const float*)d_in[24];
  const float* Wc        = (const float*)d_in[25];
  const float* bc        = (const float*)d_in[26];
  const float* bn_g      = (const float*)d_in[27];
  const float* bn_b      = (const float*)d_in[28];
  const float* Wskip     = (const float*)d_in[29];
  const float* bskip     = (const float*)d_in[30];
  const float* fc_W      = (const float*)d_in[31];
  const float* fc_b      = (const float*)d_in[32];
  const float* out_W     = (const float*)d_in[33];
  const float* out_b     = (const float*)d_in[34];

  float* ws = (float*)d_ws;
  size_t off = 0;
  float* nf    = ws + off; off += (size_t)N_NODES * CDIM;
  float* agg   = ws + off; off += (size_t)N_NODES * HCDIM;
  float* o     = ws + off; off += (size_t)N_NODES * CDIM;
  float* cbv   = ws + off; off += 768;
  float* ball  = ws + off; off += QKPW;
  float* csum  = ws + off; off += CDIM;
  float* csum2 = ws + off; off += CDIM;
  float* feats = ws + off; off += (size_t)N_GRAPH * 167;
  u16* efb   = (u16*)(ws + off); off += (size_t)N_EDGES * 64;       // E*128 u16
  u16* WcT   = (u16*)(ws + off); off += 65536;                      // 1024*128 u16
  u16* WmTb  = (u16*)(ws + off); off += 24576;                      // 128*384 u16
  u16* nfb   = (u16*)(ws + off); off += (size_t)N_NODES * 64;       // N*128 u16
  u16* qkp   = (u16*)(ws + off); off += (size_t)N_NODES * (QKPW/2); // N*2176 u16
  u16* WallT = (u16*)(ws + off); off += (size_t)QKPW * 64;          // 2176*128 u16
  u16* WcTw  = (u16*)(ws + off); off += 16384;                      // 128*256 u16
  u16* xpad  = (u16*)(ws + off); off += (size_t)N_NODES * 48;       // N*96 u16
  u16* epad  = (u16*)(ws + off); off += (size_t)N_EDGES * 32;       // E*64 u16
  u16* atomWT= (u16*)(ws + off); off += 6144;                       // 128*96 u16
  u16* WeT2  = (u16*)(ws + off); off += 4096;                       // 128*64 u16

  // ---- one-time: pack inputs, initial MFMA GEMMs ----
  pack_init_kernel<<<dim3(256, 4), 256, 0, stream>>>(x, edge_attr, atom_W, edge_W,
                                                     xpad, epad, atomWT, WeT2);
  mfma_gemm_kernel<0, 0, 0><<<dim3(2, 79), 256, 0, stream>>>(
      xpad, atomWT, atom_b, nf, nfb, nullptr, nullptr, N_NODES, 96, CDIM);
  mfma_gemm_kernel<1, 0, 0><<<dim3(2, 782), 256, 0, stream>>>(
      epad, WeT2, edge_b, efb, nullptr, nullptr, nullptr, N_EDGES, 64, CDIM);

  for (int i = 0; i < 2; ++i) {
    prep_kernel<<<dim3(1800), 256, 0, stream>>>(
        Wv + (size_t)i * CDIM * HCDIM, We + (size_t)i * CDIM * HCDIM,
        Wmu + (size_t)i * C3DIM * C3DIM,
        Wq + (size_t)i * CDIM * HCDIM, Wk + (size_t)i * CDIM * HCDIM,
        Wc + (size_t)i * HCDIM * CDIM, Wskip + (size_t)i * CDIM * CDIM,
        Wm + (size_t)i * C3DIM * CDIM, bmu + i * C3DIM, bv + i * HCDIM,
        bq + i * HCDIM, bk + i * HCDIM, bskip + i * CDIM,
        WallT, WcT, WcTw, WmTb, cbv, ball, agg, csum, csum2);

    // qkp = nfb @ [Wq|Wk|WP12|Wskip]  (N=2176, bf16 out)
    mfma_gemm_kernel<1, 0, 0><<<dim3(QKPW / 64, 79), 256, 0, stream>>>(
        nfb, WallT, ball, qkp, nullptr, nullptr, nullptr, N_NODES, CDIM, QKPW);

    edge_kernel<<<dim3(N_EDGES / 16 * 2), dim3(256), 0, stream>>>(
        qkp, efb, ei, WcT, cbv,
        ln_a_g + i * C3DIM, ln_a_b + i * C3DIM,
        WmTb, bm + i * CDIM,
        ln_m_g + i * CDIM, ln_m_b + i * CDIM, agg, N_EDGES);

    // o = agg @ Wc + bc  (A fp32 converted in-register; BN stats fused)
    mfma_gemm_kernel<0, 1, 1><<<dim3(2, 79), 256, 0, stream>>>(
        agg, WcTw, bc + i * CDIM, o, nullptr, csum, csum2, N_NODES, HCDIM, CDIM);

    bn_silu_skip_kernel<<<dim3((N_NODES * CDIM + 255) / 256), dim3(256), 0, stream>>>(
        o, qkp, csum, csum2, bn_g + i * CDIM, bn_b + i * CDIM, nf, nfb);
  }

  poolfeats_kernel<<<dim3(N_GRAPH), 256, 0, stream>>>(nf, batch, pge, cse, feats);
  fcout_kernel<<<dim3(N_GRAPH), 256, 0, stream>>>(feats, fc_W, fc_b, out_W, out_b,
                                                  (float*)d_out);
}